// Round 11
// baseline (1276.107 us; speedup 1.0000x reference)
//
#include <hip/hip_runtime.h>
#include <math.h>

// AttentionOCR: B=512, P=64, CIN=512, HID=512, EMB=512, NCLS=96, T=30
static constexpr int BATCH = 512;
static constexpr int PPOS  = 64;
static constexpr int HIDC  = 512;

typedef __attribute__((ext_vector_type(8))) short bf8;   // 8 bf16 = 4 VGPRs
typedef __attribute__((ext_vector_type(4))) short s4v;
typedef __attribute__((ext_vector_type(4))) float f4;

static __device__ __forceinline__ float sigmoidf_(float x) { return 1.f / (1.f + expf(-x)); }

static __device__ __forceinline__ short f2bf(float x) {
  unsigned u = __float_as_uint(x);
  u = u + 0x7FFF + ((u >> 16) & 1);   // round-nearest-even to bf16
  return (short)(u >> 16);
}
static __device__ __forceinline__ float bf2f(short s) {
  return __uint_as_float(((unsigned)(unsigned short)s) << 16);
}

// async global->LDS 16B per lane: LDS dest is wave-uniform base + lane*16 (linear).
static __device__ __forceinline__ void gld16(const short* g, short* l) {
  __builtin_amdgcn_global_load_lds((const __attribute__((address_space(1))) unsigned int*)g,
                                   (__attribute__((address_space(3))) unsigned int*)l, 16, 0, 0);
}

// ---------------- strided transpose: dst[C x R], dst[c][r] = src[r*ld + c] ----------------
__global__ void transpose_k(const float* __restrict__ src, float* __restrict__ dst, int R, int C, int ld) {
  __shared__ float tile[32][33];
  int c0 = blockIdx.x * 32, r0 = blockIdx.y * 32;
  int x = threadIdx.x;
  for (int yy = threadIdx.y; yy < 32; yy += 8) {
    int r = r0 + yy, c = c0 + x;
    if (r < R && c < C) tile[yy][x] = src[(size_t)r * ld + c];
  }
  __syncthreads();
  for (int yy = threadIdx.y; yy < 32; yy += 8) {
    int c = c0 + yy, r = r0 + x;
    if (r < R && c < C) dst[(size_t)c * R + r] = tile[x][yy];
  }
}

// ---------------- bfused[n] = bih[n] + bhh[n] + dot(Wih[n,:], bc) ----------------
__global__ void bfuse_k(const float* __restrict__ Wih, const float* __restrict__ bc,
                        const float* __restrict__ bih, const float* __restrict__ bhh,
                        float* __restrict__ bf) {
  int n = blockIdx.x * 256 + threadIdx.x;  // < 2048
  float s = bih[n] + bhh[n];
  const float* w = Wih + (size_t)n * 512;
  for (int m = 0; m < 512; m++) s += w[m] * bc[m];
  bf[n] = s;
}

// ---- split fp32 -> bf16 hi/lo (row-major) ----
__global__ void split_k(const float* __restrict__ src, short* __restrict__ hi, short* __restrict__ lo, int n) {
  int i = blockIdx.x * 256 + threadIdx.x;
  if (i < n) {
    float x = src[i];
    short h = f2bf(x);
    hi[i] = h;
    lo[i] = f2bf(x - bf2f(h));
  }
}

// ---- vectorized split of features: fp32 [32768x512] -> bf16 hi/lo ----
__global__ void fsplit_k(const float* __restrict__ src, short* __restrict__ hi, short* __restrict__ lo) {
  int i = blockIdx.x * 256 + threadIdx.x;  // over float4s
  float4 v = ((const float4*)src)[i];
  float a[4] = {v.x, v.y, v.z, v.w};
  s4v h4, l4;
#pragma unroll
  for (int j = 0; j < 4; j++) {
    short h = f2bf(a[j]);
    h4[j] = h;
    l4[j] = f2bf(a[j] - bf2f(h));
  }
  ((s4v*)hi)[i] = h4;
  ((s4v*)lo)[i] = l4;
}

// ---- fragment-pack + split: P[cg][kf][lane][8] = S[cg*16 + (lane&15)][kf*32 + (lane>>4)*8 + j] ----
__global__ void pack_split_k(const float* __restrict__ src, int ld,
                             short* __restrict__ hi, short* __restrict__ lo) {
  int idx = blockIdx.x * 256 + threadIdx.x;
  int j = idx & 7, lane = (idx >> 3) & 63, kf = (idx >> 9) & 15, cg = idx >> 13;
  int n = cg * 16 + (lane & 15);
  int k = kf * 32 + ((lane >> 4) << 3) + j;
  float v = src[(size_t)n * ld + k];
  short h = f2bf(v);
  hi[idx] = h;
  lo[idx] = f2bf(v - bf2f(h));
}

// ---- BTg packed from tmpT (row-major in k) + Whh: coalesced 32B-granule reads ----
__global__ void build_btg_pack_k(const float* __restrict__ tmpT, const float* __restrict__ Whh,
                                 short* __restrict__ hi, short* __restrict__ lo) {
  int idx = blockIdx.x * 256 + threadIdx.x;  // < 2097152
  int j = idx & 7, lane = (idx >> 3) & 63, kf = (idx >> 9) & 31, cg = idx >> 14;
  int cp = cg * 16 + (lane & 15);
  int k = kf * 32 + ((lane >> 4) << 3) + j;
  int jj = cp >> 2, g = cp & 3;
  int n = g * 512 + jj;
  float v = (k < 512) ? tmpT[(size_t)n * 512 + k] : Whh[(size_t)n * 512 + (k - 512)];
  short h = f2bf(v);
  hi[idx] = h;
  lo[idx] = f2bf(v - bf2f(h));
}

// ---- Gemb_p[96 x 2048] = (emb_table @ tmp[0:512]) + bfused, columns permuted. 12 e-rows/block ----
__global__ __launch_bounds__(256) void gemb_k(const float* __restrict__ emb_table, const float* __restrict__ tmp,
                                              const float* __restrict__ bfused, float* __restrict__ Gemb_p) {
  __shared__ float emb_s[12][512];
  int tid = threadIdx.x;
  int n0 = blockIdx.x * 256;
  int e0 = blockIdx.y * 12;
  for (int i = tid; i < 12 * 512; i += 256)
    emb_s[i >> 9][i & 511] = emb_table[(size_t)(e0 + (i >> 9)) * 512 + (i & 511)];
  __syncthreads();
  int n = n0 + tid;
  float acc[12] = {};
  for (int k = 0; k < 512; k++) {
    float w = tmp[(size_t)k * 2048 + n];
#pragma unroll
    for (int e = 0; e < 12; e++) acc[e] += emb_s[e][k] * w;
  }
  int cp = (n & 511) * 4 + (n >> 9);
  float b = bfused[n];
#pragma unroll
  for (int e = 0; e < 12; e++) Gemb_p[(size_t)(e0 + e) * 2048 + cp] = acc[e] + b;
}

// ---- Za[96 x 512] = emb_table @ WaT_emb + ba. 12 e-rows/block ----
__global__ __launch_bounds__(256) void za_k(const float* __restrict__ emb_table, const float* __restrict__ WaT_emb,
                                            const float* __restrict__ ba, float* __restrict__ Za) {
  __shared__ float emb_s[12][512];
  int tid = threadIdx.x;
  int n0 = blockIdx.x * 256;
  int e0 = blockIdx.y * 12;
  for (int i = tid; i < 12 * 512; i += 256)
    emb_s[i >> 9][i & 511] = emb_table[(size_t)(e0 + (i >> 9)) * 512 + (i & 511)];
  __syncthreads();
  int n = n0 + tid;
  float acc[12] = {};
  for (int k = 0; k < 512; k++) {
    float w = WaT_emb[(size_t)k * 512 + n];
#pragma unroll
    for (int e = 0; e < 12; e++) acc[e] += emb_s[e][k] * w;
  }
  float b = ba[n];
#pragma unroll
  for (int e = 0; e < 12; e++) Za[(size_t)(e0 + e) * 512 + n] = acc[e] + b;
}

// ---- feats: C[32768x512] = features @ Wfc^T (+bfc). Tile 64x128, grid 2048. (R8/R9 best config:
// 16 KB LDS, VGPR 64, ~35% occupancy.) A via async gload_lds; B packed direct from L2.
__global__ __launch_bounds__(256) void feats_mfma_k(const short* __restrict__ Fh, const short* __restrict__ Fl,
                                                    const short* __restrict__ Ph, const short* __restrict__ Pl,
                                                    const float* __restrict__ bias, float* __restrict__ C) {
  __shared__ short Ah[2][64][32], Al[2][64][32];
  int blk = blockIdx.x;
  int xt = (blk >> 3) & 3;
  int ytile = (blk >> 5) * 8 + (blk & 7);
  int row0 = ytile * 64, col0 = xt * 128;
  int tid = threadIdx.x;
  int lane = tid & 63, wave = tid >> 6;
  int wm = (wave & 1) * 32, wn = (wave >> 1) * 64;
  int r15 = lane & 15;
  int srow = 16 * wave + (lane >> 2);
  int sg = (lane & 3) ^ (srow & 3);
  const short* gAh = Fh + (size_t)(row0 + srow) * 512 + (sg << 3);
  const short* gAl = Fl + (size_t)(row0 + srow) * 512 + (sg << 3);
  int cg0 = (col0 + wn) >> 4;
  const short* pbh = Ph + (size_t)cg0 * 8192 + lane * 8;
  const short* pbl = Pl + (size_t)cg0 * 8192 + lane * 8;
  bf8 cbh[4], cbl[4], nbh[4], nbl[4];
#pragma unroll
  for (int c = 0; c < 4; c++) {
    cbh[c] = *(const bf8*)(pbh + c * 8192);
    cbl[c] = *(const bf8*)(pbl + c * 8192);
  }
  gld16(gAh, &Ah[0][16 * wave][0]);
  gld16(gAl, &Al[0][16 * wave][0]);
  __syncthreads();
  f4 acc[2][4] = {};
  for (int kt = 0; kt < 16; kt++) {
    int buf = kt & 1;
    if (kt + 1 < 16) {
      gld16(gAh + (kt + 1) * 32, &Ah[buf ^ 1][16 * wave][0]);
      gld16(gAl + (kt + 1) * 32, &Al[buf ^ 1][16 * wave][0]);
#pragma unroll
      for (int c = 0; c < 4; c++) {
        nbh[c] = *(const bf8*)(pbh + c * 8192 + (kt + 1) * 512);
        nbl[c] = *(const bf8*)(pbl + c * 8192 + (kt + 1) * 512);
      }
    }
    bf8 fah[2], fal[2];
#pragma unroll
    for (int r = 0; r < 2; r++) {
      int row = wm + r * 16 + r15;
      int off = row * 64 + ((((lane >> 4) ^ (r15 & 3)) << 4));
      fah[r] = *(const bf8*)((const char*)&Ah[buf][0][0] + off);
      fal[r] = *(const bf8*)((const char*)&Al[buf][0][0] + off);
    }
#pragma unroll
    for (int r = 0; r < 2; r++)
#pragma unroll
      for (int c = 0; c < 4; c++) {
        acc[r][c] = __builtin_amdgcn_mfma_f32_16x16x32_bf16(fah[r], cbh[c], acc[r][c], 0, 0, 0);
        acc[r][c] = __builtin_amdgcn_mfma_f32_16x16x32_bf16(fal[r], cbh[c], acc[r][c], 0, 0, 0);
        acc[r][c] = __builtin_amdgcn_mfma_f32_16x16x32_bf16(fah[r], cbl[c], acc[r][c], 0, 0, 0);
      }
    __syncthreads();   // drains gload_lds (kt+1 landed) + protects buf reuse
#pragma unroll
    for (int c = 0; c < 4; c++) { cbh[c] = nbh[c]; cbl[c] = nbl[c]; }
  }
#pragma unroll
  for (int r = 0; r < 2; r++)
#pragma unroll
    for (int c = 0; c < 4; c++) {
      int col = col0 + wn + c * 16 + r15;
      float bv = bias[col];
#pragma unroll
      for (int i = 0; i < 4; i++) {
        int row = row0 + wm + r * 16 + (lane >> 4) * 4 + i;
        C[(size_t)row * 512 + col] = acc[r][c][i] + bv;
      }
    }
}

// ---- tmp GEMM (setup): rows<512 -> tmp[512x2048] (gemb); rows>=512 -> tmpT[2048x512] (build_btg) ----
__global__ __launch_bounds__(256) void tmp_mfma_k(const float* __restrict__ A,
                                                  const short* __restrict__ BTh, const short* __restrict__ BTl,
                                                  float* __restrict__ C, float* __restrict__ CT) {
  __shared__ short Ah[2][64][40], Al[2][64][40], Bh[2][128][40], Bl[2][128][40];
  int row0 = blockIdx.y * 64, col0 = blockIdx.x * 128;
  int tid = threadIdx.x;
  int lane = tid & 63, wave = tid >> 6;
  int wm = (wave & 1) * 32, wn = (wave >> 1) * 64;
  int r15 = lane & 15, q8 = (lane >> 4) * 8;
  int smA = tid >> 2, skA = (tid & 3) * 8;
  int smB = tid >> 1, skB = (tid & 1) * 16;
  const float* Ap = A + (size_t)(row0 + smA) * 512 + skA;
  const short* Bhp = BTh + (size_t)(col0 + smB) * 512 + skB;
  const short* Blp = BTl + (size_t)(col0 + smB) * 512 + skB;
  float4 a0 = *(const float4*)Ap, a1 = *(const float4*)(Ap + 4);
  bf8 bh0 = *(const bf8*)Bhp, bh1 = *(const bf8*)(Bhp + 8);
  bf8 bl0 = *(const bf8*)Blp, bl1 = *(const bf8*)(Blp + 8);
  f4 acc[2][4] = {};
  for (int kt = 0; kt < 16; kt++) {
    int buf = kt & 1;
    {
      float av[8] = {a0.x, a0.y, a0.z, a0.w, a1.x, a1.y, a1.z, a1.w};
      bf8 ahv, alv;
#pragma unroll
      for (int i = 0; i < 8; i++) {
        short h = f2bf(av[i]);
        ahv[i] = h;
        alv[i] = f2bf(av[i] - bf2f(h));
      }
      *(bf8*)&Ah[buf][smA][skA] = ahv;
      *(bf8*)&Al[buf][smA][skA] = alv;
      *(bf8*)&Bh[buf][smB][skB] = bh0;
      *(bf8*)&Bh[buf][smB][skB + 8] = bh1;
      *(bf8*)&Bl[buf][smB][skB] = bl0;
      *(bf8*)&Bl[buf][smB][skB + 8] = bl1;
    }
    if (kt + 1 < 16) {
      Ap += 32; Bhp += 32; Blp += 32;
      a0 = *(const float4*)Ap; a1 = *(const float4*)(Ap + 4);
      bh0 = *(const bf8*)Bhp; bh1 = *(const bf8*)(Bhp + 8);
      bl0 = *(const bf8*)Blp; bl1 = *(const bf8*)(Blp + 8);
    }
    __syncthreads();
    bf8 fah[2], fal[2], fbh[4], fbl[4];
#pragma unroll
    for (int r = 0; r < 2; r++) {
      fah[r] = *(const bf8*)&Ah[buf][wm + r * 16 + r15][q8];
      fal[r] = *(const bf8*)&Al[buf][wm + r * 16 + r15][q8];
    }
#pragma unroll
    for (int c = 0; c < 4; c++) {
      fbh[c] = *(const bf8*)&Bh[buf][wn + c * 16 + r15][q8];
      fbl[c] = *(const bf8*)&Bl[buf][wn + c * 16 + r15][q8];
    }
#pragma unroll
    for (int r = 0; r < 2; r++)
#pragma unroll
      for (int c = 0; c < 4; c++) {
        acc[r][c] = __builtin_amdgcn_mfma_f32_16x16x32_bf16(fah[r], fbh[c], acc[r][c], 0, 0, 0);
        acc[r][c] = __builtin_amdgcn_mfma_f32_16x16x32_bf16(fal[r], fbh[c], acc[r][c], 0, 0, 0);
        acc[r][c] = __builtin_amdgcn_mfma_f32_16x16x32_bf16(fah[r], fbl[c], acc[r][c], 0, 0, 0);
      }
  }
#pragma unroll
  for (int r = 0; r < 2; r++)
#pragma unroll
    for (int c = 0; c < 4; c++) {
      int col = col0 + wn + c * 16 + r15;
#pragma unroll
      for (int i = 0; i < 4; i++) {
        int row = row0 + wm + r * 16 + (lane >> 4) * 4 + i;
        if (row < 512) C[(size_t)row * 2048 + col] = acc[r][c][i];
        else           CT[(size_t)col * 512 + (row - 512)] = acc[r][c][i];
      }
    }
}

// ---- per-step z GEMM: zbuf[2][512x512] = h_prev @ WaH^T (K-split halves), tile 32x32, BK=64 ----
__global__ __launch_bounds__(256) void z_mfma_k(const short* __restrict__ h_hi, const short* __restrict__ h_lo,
                                                const short* __restrict__ Ph, const short* __restrict__ Pl,
                                                float* __restrict__ zbuf) {
  __shared__ short Ah[2][32][72], Al[2][32][72];
  int tid = threadIdx.x;
  int lane = tid & 63, wave = tid >> 6;
  int wm = (wave & 1) * 16, wn = (wave >> 1) * 16;
  int r15 = lane & 15, q4 = (lane >> 4) * 4, q8 = (lane >> 4) * 8;
  int row0 = blockIdx.y * 32, col0 = blockIdx.x * 32;
  int kz = blockIdx.z * 256;
  int sm = tid >> 3, sk = (tid & 7) * 8;
  const short* ahp = h_hi + (size_t)(row0 + sm) * 512 + kz + sk;
  const short* alp = h_lo + (size_t)(row0 + sm) * 512 + kz + sk;
  int cg = (col0 + wn) >> 4;
  const short* pbh = Ph + (size_t)cg * 8192 + (size_t)blockIdx.z * 4096 + lane * 8;
  const short* pbl = Pl + (size_t)cg * 8192 + (size_t)blockIdx.z * 4096 + lane * 8;
  bf8 ah = *(const bf8*)ahp, al = *(const bf8*)alp;
  bf8 bhc[2], blc[2], bhn[2], bln[2];
#pragma unroll
  for (int ks = 0; ks < 2; ks++) {
    bhc[ks] = *(const bf8*)(pbh + ks * 512);
    blc[ks] = *(const bf8*)(pbl + ks * 512);
  }
  f4 acc = {};
#pragma unroll 2
  for (int kt = 0; kt < 4; kt++) {
    int buf = kt & 1;
    *(bf8*)&Ah[buf][sm][sk] = ah;
    *(bf8*)&Al[buf][sm][sk] = al;
    if (kt + 1 < 4) {
      ahp += 64; alp += 64;
      ah = *(const bf8*)ahp; al = *(const bf8*)alp;
#pragma unroll
      for (int ks = 0; ks < 2; ks++) {
        bhn[ks] = *(const bf8*)(pbh + ((kt + 1) * 2 + ks) * 512);
        bln[ks] = *(const bf8*)(pbl + ((kt + 1) * 2 + ks) * 512);
      }
    }
    __syncthreads();
#pragma unroll
    for (int ks = 0; ks < 2; ks++) {
      bf8 fah = *(const bf8*)&Ah[buf][wm + r15][ks * 32 + q8];
      bf8 fal = *(const bf8*)&Al[buf][wm + r15][ks * 32 + q8];
      acc = __builtin_amdgcn_mfma_f32_16x16x32_bf16(fah, bhc[ks], acc, 0, 0, 0);
      acc = __builtin_amdgcn_mfma_f32_16x16x32_bf16(fal, bhc[ks], acc, 0, 0, 0);
      acc = __builtin_amdgcn_mfma_f32_16x16x32_bf16(fah, blc[ks], acc, 0, 0, 0);
    }
#pragma unroll
    for (int ks = 0; ks < 2; ks++) { bhc[ks] = bhn[ks]; blc[ks] = bln[ks]; }
  }
  float* zo = zbuf + (size_t)blockIdx.z * (512 * 512);
  int col = col0 + wn + r15;
#pragma unroll
  for (int i = 0; i < 4; i++)
    zo[(size_t)(row0 + wm + q4 + i) * 512 + col] = acc[i];
}

// ---- attn finish: softmax(z+Za[id]) -> scores -> softmax(P) -> ctx (bf16 hi/lo). ----
__global__ __launch_bounds__(512) void attn_fin_k(const float* __restrict__ zbuf,
                                                  const int* __restrict__ targets, int t, int T,
                                                  const float* __restrict__ Za, const float* __restrict__ feats,
                                                  short* __restrict__ ctx_hi, short* __restrict__ ctx_lo) {
  __shared__ float a_s[512];
  __shared__ float redm[8], reds[8];
  __shared__ float sc_s[64];
  __shared__ float w_s[64];
  __shared__ float cpart[8][512];
  int tid = threadIdx.x;
  int wid = tid >> 6, lane = tid & 63;
  int b = blockIdx.x;
  int id = (t == 0) ? 0 : targets[b * T + t - 1];

  const float4* fbase = (const float4*)(feats + (size_t)b * PPOS * 512);
  float4 f1[8], f2[8];
#pragma unroll
  for (int q = 0; q < 8; q++) {
    int p = wid * 8 + q;
    f1[q] = fbase[(size_t)p * 128 + lane];
    f2[q] = fbase[(size_t)p * 128 + 64 + lane];
  }

  float zv = zbuf[(size_t)b * 512 + tid] + zbuf[(size_t)(512 * 512) + b * 512 + tid]
           + Za[(size_t)id * 512 + tid];
  float m = zv;
#pragma unroll
  for (int off = 32; off; off >>= 1) m = fmaxf(m, __shfl_xor(m, off, 64));
  if (lane == 0) redm[wid] = m;
  __syncthreads();
  float M = redm[0];
#pragma unroll
  for (int w = 1; w < 8; w++) M = fmaxf(M, redm[w]);
  float e = expf(zv - M);
  float s = e;
#pragma unroll
  for (int off = 32; off; off >>= 1) s += __shfl_xor(s, off, 64);
  if (lane == 0) reds[wid] = s;
  __syncthreads();
  float S = 0.f;
#pragma unroll
  for (int w = 0; w < 8; w++) S += reds[w];
  a_s[tid] = e * (1.f / S);
  __syncthreads();

  float4 a1 = ((const float4*)a_s)[lane];
  float4 a2 = ((const float4*)a_s)[lane + 64];
#pragma unroll
  for (int q = 0; q < 8; q++) {
    float d = f1[q].x * a1.x + f1[q].y * a1.y + f1[q].z * a1.z + f1[q].w * a1.w
            + f2[q].x * a2.x + f2[q].y * a2.y + f2[q].z * a2.z + f2[q].w * a2.w;
#pragma unroll
    for (int off = 32; off; off >>= 1) d += __shfl_xor(d, off, 64);
    if (lane == 0) sc_s[wid * 8 + q] = d;
  }
  __syncthreads();

  if (wid == 0) {
    float v = sc_s[lane];
    float mm = v;
#pragma unroll
    for (int off = 32; off; off >>= 1) mm = fmaxf(mm, __shfl_xor(mm, off, 64));
    float ee = expf(v - mm);
    float ss = ee;
#pragma unroll
    for (int off = 32; off; off >>= 1) ss += __shfl_xor(ss, off, 64);
    w_s[lane] = ee / ss;
  }
  __syncthreads();

  float4 c1 = {0.f, 0.f, 0.f, 0.f}, c2 = {0.f, 0.f, 0.f, 0.f};
#pragma unroll
  for (int q = 0; q < 8; q++) {
    float wp = w_s[wid * 8 + q];
    c1.x += wp * f1[q].x; c1.y += wp * f1[q].y; c1.z += wp * f1[q].z; c1.w += wp * f1[q].w;
    c2.x += wp * f2[q].x; c2.y += wp * f2[q].y; c2.z += wp * f2[q].z; c2.w += wp * f2[q].w;
  }
  ((float4*)&cpart[wid][0])[lane] = c1;
  ((float4*)&cpart[wid][256])[lane] = c2;
  __syncthreads();

  float acc = 0.f;
#pragma unroll
  for (int w = 0; w < 8; w++) acc += cpart[w][tid];
  short hh = f2bf(acc);
  ctx_hi[(size_t)b * 512 + tid] = hh;
  ctx_lo[(size_t)b * 512 + tid] = f2bf(acc - bf2f(hh));
}

// ---- gates: [ctx|h][512x1024] @ Bcat (+Gemb[id]) -> LSTM. Tile 32x64, BK=64, 512 blocks. ----
// XCD-swizzled 1D grid: bid&7 -> 256-col span (per-XCD L2 holds its 1MB B slice + A stream).
__global__ __launch_bounds__(256) void gates_mfma_k(const short* __restrict__ ctx_hi, const short* __restrict__ ctx_lo,
                                                    const short* __restrict__ h_hi_in, const short* __restrict__ h_lo_in,
                                                    const int* __restrict__ targets, int t, int T,
                                                    const short* __restrict__ Ph, const short* __restrict__ Pl,
                                                    const float* __restrict__ Gemb_p,
                                                    float* __restrict__ cbuf,
                                                    short* __restrict__ h_hi_out, short* __restrict__ h_lo_out) {
  __shared__ short Ah[2][32][72], Al[2][32][72];
  __shared__ float Cs[32][68];
  int tid = threadIdx.x;
  int lane = tid & 63, wave = tid >> 6;
  int wn = wave * 16;
  int r15 = lane & 15, q8 = (lane >> 4) * 8;
  int bid = blockIdx.x;
  int xcd = bid & 7, sub = bid >> 3;           // sub < 64: 4 col-subblocks x 16 row-panels
  int col0 = xcd * 256 + (sub & 3) * 64;
  int row0 = (sub >> 2) * 32;
  int smA = tid >> 3, skA = (tid & 7) * 8;   // 32 rows x 64k, 8 shorts/thread
  const short* actx_h = ctx_hi + (size_t)(row0 + smA) * 512;
  const short* actx_l = ctx_lo + (size_t)(row0 + smA) * 512;
  const short* ahst_h = h_hi_in + (size_t)(row0 + smA) * 512;
  const short* ahst_l = h_lo_in + (size_t)(row0 + smA) * 512;
  int cg = (col0 >> 4) + wave;
  const short* pbh = Ph + (size_t)cg * 16384 + lane * 8;   // + (kt*2+ks)*512
  const short* pbl = Pl + (size_t)cg * 16384 + lane * 8;
  bf8 ah = *(const bf8*)(actx_h + skA), al = *(const bf8*)(actx_l + skA);
  bf8 bhc[2], blc[2], bhn[2], bln[2];
#pragma unroll
  for (int ks = 0; ks < 2; ks++) {
    bhc[ks] = *(const bf8*)(pbh + ks * 512);
    blc[ks] = *(const bf8*)(pbl + ks * 512);
  }
  f4 acc[2] = {};
#pragma unroll 2
  for (int kt = 0; kt < 16; kt++) {
    int buf = kt & 1;
    *(bf8*)&Ah[buf][smA][skA] = ah;
    *(bf8*)&Al[buf][smA][skA] = al;
    if (kt + 1 < 16) {
      int kk = (kt + 1) * 64 + skA;
      if (kk < 512) {
        ah = *(const bf8*)(actx_h + kk);
        al = *(const bf8*)(actx_l + kk);
      } else {
        ah = *(const bf8*)(ahst_h + kk - 512);
        al = *(const bf8*)(ahst_l + kk - 512);
      }
#pragma unroll
      for (int ks = 0; ks < 2; ks++) {
        bhn[ks] = *(const bf8*)(pbh + ((kt + 1) * 2 + ks) * 512);
        bln[ks] = *(const bf8*)(pbl + ((kt + 1) * 2 + ks) * 512);
      }
    }
    __syncthreads();
#pragma unroll
    for (int ks = 0; ks < 2; ks++) {
      bf8 fah[2], fal[2];
#pragma unroll
      for (int r = 0; r < 2; r++) {
        fah[r] = *(const bf8*)&Ah[buf][r * 16 + r15][ks * 32 + q8];
        fal[r] = *(const bf8*)&Al[buf][r * 16 + r15][ks * 32 + q8];
      }
#pragma unroll
      for (int r = 0; r < 2; r++) {
        acc[r] = __builtin_amdgcn_mfma_f32_16x16x32_bf16(fah[r], bhc[ks], acc[r], 0, 0, 0);
        acc[r] = __builtin_amdgcn_mfma_f32_16x16x32_bf16(fal[r], bhc[ks], acc[r], 0, 0, 0);
        acc[r] = __builtin_amdgcn_mfma_f32_16x16x32_bf16(fah[r], blc[ks], acc[r], 0, 0, 0);
      }
    }
#pragma unroll
    for (int ks = 0; ks < 2; ks++) { bhc[ks] = bhn[ks]; blc[ks] = bln[ks]; }
  }
  // stage C tile to LDS (MFMA C layout -> row/col), then LSTM epilogue
#pragma unroll
  for (int r = 0; r < 2; r++)
#pragma unroll
    for (int i = 0; i < 4; i++)
      Cs[r * 16 + (lane >> 4) * 4 + i][wn + r15] = acc[r][i];
  __syncthreads();
#pragma unroll
  for (int it = 0; it < 2; it++) {
    int idx = it * 256 + tid;
    int row = idx >> 4, jj = idx & 15;
    int b = row0 + row;
    int jg = (col0 >> 2) + jj;
    int id = (t == 0) ? 0 : targets[b * T + t - 1];
    float4 g4 = *(const float4*)(Gemb_p + (size_t)id * 2048 + col0 + jj * 4);
    float ig = sigmoidf_(Cs[row][jj * 4 + 0] + g4.x);
    float fg = sigmoidf_(Cs[row][jj * 4 + 1] + g4.y);
    float gg = tanhf(Cs[row][jj * 4 + 2] + g4.z);
    float og = sigmoidf_(Cs[row][jj * 4 + 3] + g4.w);
    float cn = fg * cbuf[(size_t)b * 512 + jg] + ig * gg;
    float hn = og * tanhf(cn);
    cbuf[(size_t)b * 512 + jg] = cn;
    short hh = f2bf(hn);
    h_hi_out[(size_t)b * 512 + jg] = hh;
    h_lo_out[(size_t)b * 512 + jg] = f2bf(hn - bf2f(hh));
  }
}

// ---- out GEMM: out = h_hist(bf16 hi/lo) @ Wo^T + bo. M=T*512, N=96, tile 64x96, split-bf16 MFMA ----
__global__ __launch_bounds__(256) void out_mfma_k(const short* __restrict__ Hh, const short* __restrict__ Hl,
                                                  const short* __restrict__ Ph, const short* __restrict__ Pl,
                                                  const float* __restrict__ bo, float* __restrict__ out, int T) {
  __shared__ short Ah[2][64][40], Al[2][64][40];
  int tid = threadIdx.x;
  int lane = tid & 63, wave = tid >> 6;
  int wm = (wave & 1) * 32, wn = (wave >> 1) * 48;
  int r15 = lane & 15, q8 = (lane >> 4) * 8;
  int row0 = blockIdx.x * 64;
  int smA = tid >> 2, skA = (tid & 3) * 8;
  const short* ahp = Hh + (size_t)(row0 + smA) * 512 + skA;
  const short* alp = Hl + (size_t)(row0 + smA) * 512 + skA;
  int cg0 = wn >> 4;
  const short* pbh = Ph + (size_t)cg0 * 8192 + lane * 8;
  const short* pbl = Pl + (size_t)cg0 * 8192 + lane * 8;
  bf8 ah = *(const bf8*)ahp, al = *(const bf8*)alp;
  bf8 bhc[3], blc[3], bhn[3], bln[3];
#pragma unroll
  for (int c = 0; c < 3; c++) {
    bhc[c] = *(const bf8*)(pbh + c * 8192);
    blc[c] = *(const bf8*)(pbl + c * 8192);
  }
  f4 acc[2][3] = {};
#pragma unroll 2
  for (int kt = 0; kt < 16; kt++) {
    int buf = kt & 1;
    *(bf8*)&Ah[buf][smA][skA] = ah;
    *(bf8*)&Al[buf][smA][skA] = al;
    if (kt + 1 < 16) {
      ahp += 32; alp += 32;
      ah = *(const bf8*)ahp; al = *(const bf8*)alp;
#pragma unroll
      for (int c = 0; c < 3; c++) {
        bhn[c] = *(const bf8*)(pbh + c * 8192 + (kt + 1) * 512);
        bln[c] = *(const bf8*)(pbl + c * 8192 + (kt + 1) * 512);
      }
    }
    __syncthreads();
    bf8 fah[2], fal[2];
#pragma unroll
    for (int r = 0; r < 2; r++) {
      fah[r] = *(const bf8*)&Ah[buf][wm + r * 16 + r15][q8];
      fal[r] = *(const bf8*)&Al[buf][wm + r * 16 + r15][q8];
    }
#pragma unroll
    for (int r = 0; r < 2; r++)
#pragma unroll
      for (int c = 0; c < 3; c++) {
        acc[r][c] = __builtin_amdgcn_mfma_f32_16x16x32_bf16(fah[r], bhc[c], acc[r][c], 0, 0, 0);
        acc[r][c] = __builtin_amdgcn_mfma_f32_16x16x32_bf16(fal[r], bhc[c], acc[r][c], 0, 0, 0);
        acc[r][c] = __builtin_amdgcn_mfma_f32_16x16x32_bf16(fah[r], blc[c], acc[r][c], 0, 0, 0);
      }
    __syncthreads();
#pragma unroll
    for (int c = 0; c < 3; c++) { bhc[c] = bhn[c]; blc[c] = bln[c]; }
  }
#pragma unroll
  for (int r = 0; r < 2; r++)
#pragma unroll
    for (int c = 0; c < 3; c++) {
      int col = wn + c * 16 + r15;
      float bv = bo[col];
#pragma unroll
      for (int i = 0; i < 4; i++) {
        int row = row0 + wm + r * 16 + (lane >> 4) * 4 + i;
        int tt = row >> 9, bb = row & 511;
        out[((size_t)bb * T + tt) * 96 + col] = acc[r][c][i] + bv;
      }
    }
}

extern "C" void kernel_launch(void* const* d_in, const int* in_sizes, int n_in,
                              void* d_out, int out_size, void* d_ws, size_t ws_size,
                              hipStream_t stream) {
  const float* features  = (const float*)d_in[0];
  const int*   targets   = (const int*)d_in[1];
  const float* Wfc       = (const float*)d_in[3];
  const float* bfc       = (const float*)d_in[4];
  const float* emb_table = (const float*)d_in[5];
  const float* Wa        = (const float*)d_in[6];
  const float* ba        = (const float*)d_in[7];
  const float* Wc        = (const float*)d_in[8];
  const float* bc        = (const float*)d_in[9];
  const float* Wih       = (const float*)d_in[10];
  const float* Whh       = (const float*)d_in[11];
  const float* bih       = (const float*)d_in[12];
  const float* bhh       = (const float*)d_in[13];
  const float* Wo        = (const float*)d_in[14];
  const float* bo        = (const float*)d_in[15];
  float* out = (float*)d_out;
  int T = in_sizes[1] / BATCH;  // 30

  char* base = (char*)d_ws;
  auto alloc = [&](size_t bytes) -> char* {
    char* p = base;
    base += (bytes + 255) & ~(size_t)255;
    return p;
  };
  float* feats   = (float*)alloc((size_t)BATCH * PPOS * HIDC * 4);
  short* f_hi    = (short*)alloc((size_t)BATCH * PPOS * HIDC * 2);
  short* f_lo    = (short*)alloc((size_t)BATCH * PPOS * HIDC * 2);
  float* WaT_emb = (float*)alloc(512 * 512 * 4);
  float* WcT     = (float*)alloc(1024 * 512 * 4);
  float* tmp     = (float*)alloc((size_t)512 * 2048 * 4);   // rows 0..511 (gemb)
  float* tmpT    = (float*)alloc((size_t)2048 * 512 * 4);   // rows 512..1023 transposed (build_btg)
  short* Wih_hi  = (short*)alloc((size_t)2048 * 512 * 2);
  short* Wih_lo  = (short*)alloc((size_t)2048 * 512 * 2);
  short* PBTg_hi = (short*)alloc((size_t)2048 * 1024 * 2);
  short* PBTg_lo = (short*)alloc((size_t)2048 * 1024 * 2);
  short* Pfc_hi  = (short*)alloc(512 * 512 * 2);
  short* Pfc_lo  = (short*)alloc(512 * 512 * 2);
  short* Pwa_hi  = (short*)alloc(512 * 512 * 2);
  short* Pwa_lo  = (short*)alloc(512 * 512 * 2);
  short* Pwo_hi  = (short*)alloc(96 * 512 * 2);
  short* Pwo_lo  = (short*)alloc(96 * 512 * 2);
  float* Gemb_p  = (float*)alloc(96 * 2048 * 4);
  float* Za      = (float*)alloc(96 * 512 * 4);
  float* bfused  = (float*)alloc(2048 * 4);
  float* cbuf    = (float*)alloc(BATCH * HIDC * 4);
  float* zbuf    = (float*)alloc((size_t)2 * BATCH * HIDC * 4);
  short* ctx_hi  = (short*)alloc(BATCH * HIDC * 2);
  short* ctx_lo  = (short*)alloc(BATCH * HIDC * 2);
  size_t slab = (size_t)BATCH * HIDC;                      // 262144 elems
  short* hist_hi = (short*)alloc((size_t)(T + 1) * slab * 2);
  short* hist_lo = (short*)alloc((size_t)(T + 1) * slab * 2);

  dim3 tb(32, 8);
  transpose_k<<<dim3(16, 16), tb, 0, stream>>>(Wa + 512, WaT_emb, 512, 512, 1024);
  transpose_k<<<dim3(32, 16), tb, 0, stream>>>(Wc, WcT, 512, 1024, 1024);

  // weight preprocessing
  split_k<<<(2048 * 512) / 256, 256, 0, stream>>>(Wih, Wih_hi, Wih_lo, 2048 * 512);
  pack_split_k<<<(512 * 512) / 256, 256, 0, stream>>>(Wfc, 512, Pfc_hi, Pfc_lo);
  pack_split_k<<<(512 * 512) / 256, 256, 0, stream>>>(Wa, 1024, Pwa_hi, Pwa_lo);
  pack_split_k<<<(96 * 512) / 256, 256, 0, stream>>>(Wo, 512, Pwo_hi, Pwo_lo);
  fsplit_k<<<(BATCH * PPOS * HIDC / 4) / 256, 256, 0, stream>>>(features, f_hi, f_lo);

  // tmp = WcT @ Wih^T; upper half row-major (gemb), lower half transposed (build_btg)
  tmp_mfma_k<<<dim3(16, 16), 256, 0, stream>>>(WcT, Wih_hi, Wih_lo, tmp, tmpT);

  bfuse_k<<<8, 256, 0, stream>>>(Wih, bc, bih, bhh, bfused);
  build_btg_pack_k<<<(2048 * 1024) / 256, 256, 0, stream>>>(tmpT, Whh, PBTg_hi, PBTg_lo);
  gemb_k<<<dim3(8, 8), 256, 0, stream>>>(emb_table, tmp, bfused, Gemb_p);
  za_k<<<dim3(2, 8), 256, 0, stream>>>(emb_table, WaT_emb, ba, Za);

  // feats = features @ Wfc.T + bfc, async-staged split-bf16 MFMA, tile 64x128
  feats_mfma_k<<<2048, 256, 0, stream>>>(f_hi, f_lo, Pfc_hi, Pfc_lo, bfc, feats);

  hipMemsetAsync(cbuf, 0, (size_t)BATCH * HIDC * 4, stream);
  hipMemsetAsync(hist_hi, 0, slab * 2, stream);
  hipMemsetAsync(hist_lo, 0, slab * 2, stream);

  for (int t = 0; t < T; t++) {
    const short* hin_hi = hist_hi + (size_t)t * slab;
    const short* hin_lo = hist_lo + (size_t)t * slab;
    short* hout_hi = hist_hi + (size_t)(t + 1) * slab;
    short* hout_lo = hist_lo + (size_t)(t + 1) * slab;
    z_mfma_k<<<dim3(16, 16, 2), 256, 0, stream>>>(hin_hi, hin_lo, Pwa_hi, Pwa_lo, zbuf);
    attn_fin_k<<<512, 512, 0, stream>>>(zbuf, targets, t, T, Za, feats, ctx_hi, ctx_lo);
    gates_mfma_k<<<512, 256, 0, stream>>>(ctx_hi, ctx_lo, hin_hi, hin_lo, targets, t, T,
                                          PBTg_hi, PBTg_lo, Gemb_p, cbuf, hout_hi, hout_lo);
  }
  // out = h_hist @ Wo^T + bo  (A = slabs 1..T of bf16 hi/lo history)
  out_mfma_k<<<(T * BATCH) / 64, 256, 0, stream>>>(hist_hi + slab, hist_lo + slab,
                                                   Pwo_hi, Pwo_lo, bo, out, T);
}

// Round 12
// 1250.237 us; speedup vs baseline: 1.0207x; 1.0207x over previous
//
#include <hip/hip_runtime.h>
#include <math.h>

// AttentionOCR: B=512, P=64, CIN=512, HID=512, EMB=512, NCLS=96, T=30
static constexpr int BATCH = 512;
static constexpr int PPOS  = 64;
static constexpr int HIDC  = 512;

typedef __attribute__((ext_vector_type(8))) short bf8;   // 8 bf16 = 4 VGPRs
typedef __attribute__((ext_vector_type(4))) short s4v;
typedef __attribute__((ext_vector_type(4))) float f4;

static __device__ __forceinline__ float sigmoidf_(float x) { return 1.f / (1.f + expf(-x)); }

static __device__ __forceinline__ short f2bf(float x) {
  unsigned u = __float_as_uint(x);
  u = u + 0x7FFF + ((u >> 16) & 1);   // round-nearest-even to bf16
  return (short)(u >> 16);
}
static __device__ __forceinline__ float bf2f(short s) {
  return __uint_as_float(((unsigned)(unsigned short)s) << 16);
}

// async global->LDS 16B per lane: LDS dest is wave-uniform base + lane*16 (linear).
static __device__ __forceinline__ void gld16(const short* g, short* l) {
  __builtin_amdgcn_global_load_lds((const __attribute__((address_space(1))) unsigned int*)g,
                                   (__attribute__((address_space(3))) unsigned int*)l, 16, 0, 0);
}

// ---------------- strided transpose: dst[C x R], dst[c][r] = src[r*ld + c] ----------------
__global__ void transpose_k(const float* __restrict__ src, float* __restrict__ dst, int R, int C, int ld) {
  __shared__ float tile[32][33];
  int c0 = blockIdx.x * 32, r0 = blockIdx.y * 32;
  int x = threadIdx.x;
  for (int yy = threadIdx.y; yy < 32; yy += 8) {
    int r = r0 + yy, c = c0 + x;
    if (r < R && c < C) tile[yy][x] = src[(size_t)r * ld + c];
  }
  __syncthreads();
  for (int yy = threadIdx.y; yy < 32; yy += 8) {
    int c = c0 + yy, r = r0 + x;
    if (r < R && c < C) dst[(size_t)c * R + r] = tile[x][yy];
  }
}

// ---------------- bfused[n] = bih[n] + bhh[n] + dot(Wih[n,:], bc) ----------------
__global__ void bfuse_k(const float* __restrict__ Wih, const float* __restrict__ bc,
                        const float* __restrict__ bih, const float* __restrict__ bhh,
                        float* __restrict__ bf) {
  int n = blockIdx.x * 256 + threadIdx.x;  // < 2048
  float s = bih[n] + bhh[n];
  const float* w = Wih + (size_t)n * 512;
  for (int m = 0; m < 512; m++) s += w[m] * bc[m];
  bf[n] = s;
}

// ---- split fp32 -> bf16 hi/lo (row-major) ----
__global__ void split_k(const float* __restrict__ src, short* __restrict__ hi, short* __restrict__ lo, int n) {
  int i = blockIdx.x * 256 + threadIdx.x;
  if (i < n) {
    float x = src[i];
    short h = f2bf(x);
    hi[i] = h;
    lo[i] = f2bf(x - bf2f(h));
  }
}

// ---- vectorized split of features: fp32 [32768x512] -> bf16 hi/lo ----
__global__ void fsplit_k(const float* __restrict__ src, short* __restrict__ hi, short* __restrict__ lo) {
  int i = blockIdx.x * 256 + threadIdx.x;  // over float4s
  float4 v = ((const float4*)src)[i];
  float a[4] = {v.x, v.y, v.z, v.w};
  s4v h4, l4;
#pragma unroll
  for (int j = 0; j < 4; j++) {
    short h = f2bf(a[j]);
    h4[j] = h;
    l4[j] = f2bf(a[j] - bf2f(h));
  }
  ((s4v*)hi)[i] = h4;
  ((s4v*)lo)[i] = l4;
}

// ---- fragment-pack + split: P[cg][kf][lane][8] = S[cg*16 + (lane&15)][kf*32 + (lane>>4)*8 + j] ----
__global__ void pack_split_k(const float* __restrict__ src, int ld,
                             short* __restrict__ hi, short* __restrict__ lo) {
  int idx = blockIdx.x * 256 + threadIdx.x;
  int j = idx & 7, lane = (idx >> 3) & 63, kf = (idx >> 9) & 15, cg = idx >> 13;
  int n = cg * 16 + (lane & 15);
  int k = kf * 32 + ((lane >> 4) << 3) + j;
  float v = src[(size_t)n * ld + k];
  short h = f2bf(v);
  hi[idx] = h;
  lo[idx] = f2bf(v - bf2f(h));
}

// ---- BTg packed from tmpT (row-major in k) + Whh: coalesced 32B-granule reads ----
__global__ void build_btg_pack_k(const float* __restrict__ tmpT, const float* __restrict__ Whh,
                                 short* __restrict__ hi, short* __restrict__ lo) {
  int idx = blockIdx.x * 256 + threadIdx.x;  // < 2097152
  int j = idx & 7, lane = (idx >> 3) & 63, kf = (idx >> 9) & 31, cg = idx >> 14;
  int cp = cg * 16 + (lane & 15);
  int k = kf * 32 + ((lane >> 4) << 3) + j;
  int jj = cp >> 2, g = cp & 3;
  int n = g * 512 + jj;
  float v = (k < 512) ? tmpT[(size_t)n * 512 + k] : Whh[(size_t)n * 512 + (k - 512)];
  short h = f2bf(v);
  hi[idx] = h;
  lo[idx] = f2bf(v - bf2f(h));
}

// ---- Gemb_p[96 x 2048] = (emb_table @ tmp[0:512]) + bfused, columns permuted. 4 e-rows/block ----
__global__ __launch_bounds__(256) void gemb_k(const float* __restrict__ emb_table, const float* __restrict__ tmp,
                                              const float* __restrict__ bfused, float* __restrict__ Gemb_p) {
  __shared__ float emb_s[4][512];
  int tid = threadIdx.x;
  int n0 = blockIdx.x * 256;
  int e0 = blockIdx.y * 4;
  for (int i = tid; i < 2048; i += 256)
    emb_s[i >> 9][i & 511] = emb_table[(size_t)(e0 + (i >> 9)) * 512 + (i & 511)];
  __syncthreads();
  int n = n0 + tid;
  float acc[4] = {};
  for (int k = 0; k < 512; k++) {
    float w = tmp[(size_t)k * 2048 + n];
#pragma unroll
    for (int e = 0; e < 4; e++) acc[e] += emb_s[e][k] * w;
  }
  int cp = (n & 511) * 4 + (n >> 9);
  float b = bfused[n];
#pragma unroll
  for (int e = 0; e < 4; e++) Gemb_p[(size_t)(e0 + e) * 2048 + cp] = acc[e] + b;
}

// ---- Za[96 x 512] = emb_table @ WaT_emb + ba. 4 e-rows/block ----
__global__ __launch_bounds__(256) void za_k(const float* __restrict__ emb_table, const float* __restrict__ WaT_emb,
                                            const float* __restrict__ ba, float* __restrict__ Za) {
  __shared__ float emb_s[4][512];
  int tid = threadIdx.x;
  int n0 = blockIdx.x * 256;
  int e0 = blockIdx.y * 4;
  for (int i = tid; i < 2048; i += 256)
    emb_s[i >> 9][i & 511] = emb_table[(size_t)(e0 + (i >> 9)) * 512 + (i & 511)];
  __syncthreads();
  int n = n0 + tid;
  float acc[4] = {};
  for (int k = 0; k < 512; k++) {
    float w = WaT_emb[(size_t)k * 512 + n];
#pragma unroll
    for (int e = 0; e < 4; e++) acc[e] += emb_s[e][k] * w;
  }
  float b = ba[n];
#pragma unroll
  for (int e = 0; e < 4; e++) Za[(size_t)(e0 + e) * 512 + n] = acc[e] + b;
}

// ---- feats: C[32768x512] = features @ Wfc^T (+bfc). Tile 64x128, grid 2048. (best config:
// 16 KB LDS, VGPR 64, ~35% occupancy.) A via async gload_lds; B packed direct from L2.
__global__ __launch_bounds__(256) void feats_mfma_k(const short* __restrict__ Fh, const short* __restrict__ Fl,
                                                    const short* __restrict__ Ph, const short* __restrict__ Pl,
                                                    const float* __restrict__ bias, float* __restrict__ C) {
  __shared__ short Ah[2][64][32], Al[2][64][32];
  int blk = blockIdx.x;
  int xt = (blk >> 3) & 3;
  int ytile = (blk >> 5) * 8 + (blk & 7);
  int row0 = ytile * 64, col0 = xt * 128;
  int tid = threadIdx.x;
  int lane = tid & 63, wave = tid >> 6;
  int wm = (wave & 1) * 32, wn = (wave >> 1) * 64;
  int r15 = lane & 15;
  int srow = 16 * wave + (lane >> 2);
  int sg = (lane & 3) ^ (srow & 3);
  const short* gAh = Fh + (size_t)(row0 + srow) * 512 + (sg << 3);
  const short* gAl = Fl + (size_t)(row0 + srow) * 512 + (sg << 3);
  int cg0 = (col0 + wn) >> 4;
  const short* pbh = Ph + (size_t)cg0 * 8192 + lane * 8;
  const short* pbl = Pl + (size_t)cg0 * 8192 + lane * 8;
  bf8 cbh[4], cbl[4], nbh[4], nbl[4];
#pragma unroll
  for (int c = 0; c < 4; c++) {
    cbh[c] = *(const bf8*)(pbh + c * 8192);
    cbl[c] = *(const bf8*)(pbl + c * 8192);
  }
  gld16(gAh, &Ah[0][16 * wave][0]);
  gld16(gAl, &Al[0][16 * wave][0]);
  __syncthreads();
  f4 acc[2][4] = {};
  for (int kt = 0; kt < 16; kt++) {
    int buf = kt & 1;
    if (kt + 1 < 16) {
      gld16(gAh + (kt + 1) * 32, &Ah[buf ^ 1][16 * wave][0]);
      gld16(gAl + (kt + 1) * 32, &Al[buf ^ 1][16 * wave][0]);
#pragma unroll
      for (int c = 0; c < 4; c++) {
        nbh[c] = *(const bf8*)(pbh + c * 8192 + (kt + 1) * 512);
        nbl[c] = *(const bf8*)(pbl + c * 8192 + (kt + 1) * 512);
      }
    }
    bf8 fah[2], fal[2];
#pragma unroll
    for (int r = 0; r < 2; r++) {
      int row = wm + r * 16 + r15;
      int off = row * 64 + ((((lane >> 4) ^ (r15 & 3)) << 4));
      fah[r] = *(const bf8*)((const char*)&Ah[buf][0][0] + off);
      fal[r] = *(const bf8*)((const char*)&Al[buf][0][0] + off);
    }
#pragma unroll
    for (int r = 0; r < 2; r++)
#pragma unroll
      for (int c = 0; c < 4; c++) {
        acc[r][c] = __builtin_amdgcn_mfma_f32_16x16x32_bf16(fah[r], cbh[c], acc[r][c], 0, 0, 0);
        acc[r][c] = __builtin_amdgcn_mfma_f32_16x16x32_bf16(fal[r], cbh[c], acc[r][c], 0, 0, 0);
        acc[r][c] = __builtin_amdgcn_mfma_f32_16x16x32_bf16(fah[r], cbl[c], acc[r][c], 0, 0, 0);
      }
    __syncthreads();   // drains gload_lds (kt+1 landed) + protects buf reuse
#pragma unroll
    for (int c = 0; c < 4; c++) { cbh[c] = nbh[c]; cbl[c] = nbl[c]; }
  }
#pragma unroll
  for (int r = 0; r < 2; r++)
#pragma unroll
    for (int c = 0; c < 4; c++) {
      int col = col0 + wn + c * 16 + r15;
      float bv = bias[col];
#pragma unroll
      for (int i = 0; i < 4; i++) {
        int row = row0 + wm + r * 16 + (lane >> 4) * 4 + i;
        C[(size_t)row * 512 + col] = acc[r][c][i] + bv;
      }
    }
}

// ---- tmp GEMM (setup): rows<512 -> tmp[512x2048] (gemb); rows>=512 -> tmpT[2048x512] (build_btg) ----
__global__ __launch_bounds__(256) void tmp_mfma_k(const float* __restrict__ A,
                                                  const short* __restrict__ BTh, const short* __restrict__ BTl,
                                                  float* __restrict__ C, float* __restrict__ CT) {
  __shared__ short Ah[2][64][40], Al[2][64][40], Bh[2][128][40], Bl[2][128][40];
  int row0 = blockIdx.y * 64, col0 = blockIdx.x * 128;
  int tid = threadIdx.x;
  int lane = tid & 63, wave = tid >> 6;
  int wm = (wave & 1) * 32, wn = (wave >> 1) * 64;
  int r15 = lane & 15, q8 = (lane >> 4) * 8;
  int smA = tid >> 2, skA = (tid & 3) * 8;
  int smB = tid >> 1, skB = (tid & 1) * 16;
  const float* Ap = A + (size_t)(row0 + smA) * 512 + skA;
  const short* Bhp = BTh + (size_t)(col0 + smB) * 512 + skB;
  const short* Blp = BTl + (size_t)(col0 + smB) * 512 + skB;
  float4 a0 = *(const float4*)Ap, a1 = *(const float4*)(Ap + 4);
  bf8 bh0 = *(const bf8*)Bhp, bh1 = *(const bf8*)(Bhp + 8);
  bf8 bl0 = *(const bf8*)Blp, bl1 = *(const bf8*)(Blp + 8);
  f4 acc[2][4] = {};
  for (int kt = 0; kt < 16; kt++) {
    int buf = kt & 1;
    {
      float av[8] = {a0.x, a0.y, a0.z, a0.w, a1.x, a1.y, a1.z, a1.w};
      bf8 ahv, alv;
#pragma unroll
      for (int i = 0; i < 8; i++) {
        short h = f2bf(av[i]);
        ahv[i] = h;
        alv[i] = f2bf(av[i] - bf2f(h));
      }
      *(bf8*)&Ah[buf][smA][skA] = ahv;
      *(bf8*)&Al[buf][smA][skA] = alv;
      *(bf8*)&Bh[buf][smB][skB] = bh0;
      *(bf8*)&Bh[buf][smB][skB + 8] = bh1;
      *(bf8*)&Bl[buf][smB][skB] = bl0;
      *(bf8*)&Bl[buf][smB][skB + 8] = bl1;
    }
    if (kt + 1 < 16) {
      Ap += 32; Bhp += 32; Blp += 32;
      a0 = *(const float4*)Ap; a1 = *(const float4*)(Ap + 4);
      bh0 = *(const bf8*)Bhp; bh1 = *(const bf8*)(Bhp + 8);
      bl0 = *(const bf8*)Blp; bl1 = *(const bf8*)(Blp + 8);
    }
    __syncthreads();
    bf8 fah[2], fal[2], fbh[4], fbl[4];
#pragma unroll
    for (int r = 0; r < 2; r++) {
      fah[r] = *(const bf8*)&Ah[buf][wm + r * 16 + r15][q8];
      fal[r] = *(const bf8*)&Al[buf][wm + r * 16 + r15][q8];
    }
#pragma unroll
    for (int c = 0; c < 4; c++) {
      fbh[c] = *(const bf8*)&Bh[buf][wn + c * 16 + r15][q8];
      fbl[c] = *(const bf8*)&Bl[buf][wn + c * 16 + r15][q8];
    }
#pragma unroll
    for (int r = 0; r < 2; r++)
#pragma unroll
      for (int c = 0; c < 4; c++) {
        acc[r][c] = __builtin_amdgcn_mfma_f32_16x16x32_bf16(fah[r], fbh[c], acc[r][c], 0, 0, 0);
        acc[r][c] = __builtin_amdgcn_mfma_f32_16x16x32_bf16(fal[r], fbh[c], acc[r][c], 0, 0, 0);
        acc[r][c] = __builtin_amdgcn_mfma_f32_16x16x32_bf16(fah[r], fbl[c], acc[r][c], 0, 0, 0);
      }
  }
#pragma unroll
  for (int r = 0; r < 2; r++)
#pragma unroll
    for (int c = 0; c < 4; c++) {
      int col = col0 + wn + c * 16 + r15;
#pragma unroll
      for (int i = 0; i < 4; i++) {
        int row = row0 + wm + r * 16 + (lane >> 4) * 4 + i;
        if (row < 512) C[(size_t)row * 2048 + col] = acc[r][c][i];
        else           CT[(size_t)col * 512 + (row - 512)] = acc[r][c][i];
      }
    }
}

// ---- per-step z GEMM: zbuf[2][512x512] = h_prev @ WaH^T (K-split halves), tile 32x32, BK=128 ----
// grid (16,16,2); 2 barrier iterations (12 MFMA/wave per barrier). A reg-staged; B packed direct.
__global__ __launch_bounds__(256) void z_mfma_k(const short* __restrict__ h_hi, const short* __restrict__ h_lo,
                                                const short* __restrict__ Ph, const short* __restrict__ Pl,
                                                float* __restrict__ zbuf) {
  __shared__ short Ah[2][32][136], Al[2][32][136];
  int tid = threadIdx.x;
  int lane = tid & 63, wave = tid >> 6;
  int wm = (wave & 1) * 16, wn = (wave >> 1) * 16;
  int r15 = lane & 15, q4 = (lane >> 4) * 4, q8 = (lane >> 4) * 8;
  int row0 = blockIdx.y * 32, col0 = blockIdx.x * 32;
  int kz = blockIdx.z * 256;
  int sm = tid >> 3, sk = (tid & 7) * 16;   // 32 rows x 128 k, 16 shorts/thread
  const short* ahp = h_hi + (size_t)(row0 + sm) * 512 + kz + sk;
  const short* alp = h_lo + (size_t)(row0 + sm) * 512 + kz + sk;
  int cg = (col0 + wn) >> 4;
  const short* pbh = Ph + (size_t)cg * 8192 + (size_t)blockIdx.z * 4096 + lane * 8;
  const short* pbl = Pl + (size_t)cg * 8192 + (size_t)blockIdx.z * 4096 + lane * 8;
  bf8 ah0 = *(const bf8*)ahp, ah1 = *(const bf8*)(ahp + 8);
  bf8 al0 = *(const bf8*)alp, al1 = *(const bf8*)(alp + 8);
  bf8 bhc[4], blc[4], bhn[4], bln[4];
#pragma unroll
  for (int ks = 0; ks < 4; ks++) {
    bhc[ks] = *(const bf8*)(pbh + ks * 512);
    blc[ks] = *(const bf8*)(pbl + ks * 512);
  }
  f4 acc = {};
#pragma unroll
  for (int kt = 0; kt < 2; kt++) {
    int buf = kt;
    *(bf8*)&Ah[buf][sm][sk] = ah0;
    *(bf8*)&Ah[buf][sm][sk + 8] = ah1;
    *(bf8*)&Al[buf][sm][sk] = al0;
    *(bf8*)&Al[buf][sm][sk + 8] = al1;
    if (kt + 1 < 2) {
      ahp += 128; alp += 128;
      ah0 = *(const bf8*)ahp; ah1 = *(const bf8*)(ahp + 8);
      al0 = *(const bf8*)alp; al1 = *(const bf8*)(alp + 8);
#pragma unroll
      for (int ks = 0; ks < 4; ks++) {
        bhn[ks] = *(const bf8*)(pbh + (4 + ks) * 512);
        bln[ks] = *(const bf8*)(pbl + (4 + ks) * 512);
      }
    }
    __syncthreads();
#pragma unroll
    for (int ks = 0; ks < 4; ks++) {
      bf8 fah = *(const bf8*)&Ah[buf][wm + r15][ks * 32 + q8];
      bf8 fal = *(const bf8*)&Al[buf][wm + r15][ks * 32 + q8];
      acc = __builtin_amdgcn_mfma_f32_16x16x32_bf16(fah, bhc[ks], acc, 0, 0, 0);
      acc = __builtin_amdgcn_mfma_f32_16x16x32_bf16(fal, bhc[ks], acc, 0, 0, 0);
      acc = __builtin_amdgcn_mfma_f32_16x16x32_bf16(fah, blc[ks], acc, 0, 0, 0);
    }
#pragma unroll
    for (int ks = 0; ks < 4; ks++) { bhc[ks] = bhn[ks]; blc[ks] = bln[ks]; }
  }
  float* zo = zbuf + (size_t)blockIdx.z * (512 * 512);
  int col = col0 + wn + r15;
#pragma unroll
  for (int i = 0; i < 4; i++)
    zo[(size_t)(row0 + wm + q4 + i) * 512 + col] = acc[i];
}

// ---- attn finish: softmax(z+Za[id]) -> scores -> softmax(P) -> ctx (bf16 hi/lo). ----
__global__ __launch_bounds__(512) void attn_fin_k(const float* __restrict__ zbuf,
                                                  const int* __restrict__ targets, int t, int T,
                                                  const float* __restrict__ Za, const float* __restrict__ feats,
                                                  short* __restrict__ ctx_hi, short* __restrict__ ctx_lo) {
  __shared__ float a_s[512];
  __shared__ float redm[8], reds[8];
  __shared__ float sc_s[64];
  __shared__ float w_s[64];
  __shared__ float cpart[8][512];
  int tid = threadIdx.x;
  int wid = tid >> 6, lane = tid & 63;
  int b = blockIdx.x;
  int id = (t == 0) ? 0 : targets[b * T + t - 1];

  const float4* fbase = (const float4*)(feats + (size_t)b * PPOS * 512);
  float4 f1[8], f2[8];
#pragma unroll
  for (int q = 0; q < 8; q++) {
    int p = wid * 8 + q;
    f1[q] = fbase[(size_t)p * 128 + lane];
    f2[q] = fbase[(size_t)p * 128 + 64 + lane];
  }

  float zv = zbuf[(size_t)b * 512 + tid] + zbuf[(size_t)(512 * 512) + b * 512 + tid]
           + Za[(size_t)id * 512 + tid];
  float m = zv;
#pragma unroll
  for (int off = 32; off; off >>= 1) m = fmaxf(m, __shfl_xor(m, off, 64));
  if (lane == 0) redm[wid] = m;
  __syncthreads();
  float M = redm[0];
#pragma unroll
  for (int w = 1; w < 8; w++) M = fmaxf(M, redm[w]);
  float e = expf(zv - M);
  float s = e;
#pragma unroll
  for (int off = 32; off; off >>= 1) s += __shfl_xor(s, off, 64);
  if (lane == 0) reds[wid] = s;
  __syncthreads();
  float S = 0.f;
#pragma unroll
  for (int w = 0; w < 8; w++) S += reds[w];
  a_s[tid] = e * (1.f / S);
  __syncthreads();

  float4 a1 = ((const float4*)a_s)[lane];
  float4 a2 = ((const float4*)a_s)[lane + 64];
#pragma unroll
  for (int q = 0; q < 8; q++) {
    float d = f1[q].x * a1.x + f1[q].y * a1.y + f1[q].z * a1.z + f1[q].w * a1.w
            + f2[q].x * a2.x + f2[q].y * a2.y + f2[q].z * a2.z + f2[q].w * a2.w;
#pragma unroll
    for (int off = 32; off; off >>= 1) d += __shfl_xor(d, off, 64);
    if (lane == 0) sc_s[wid * 8 + q] = d;
  }
  __syncthreads();

  if (wid == 0) {
    float v = sc_s[lane];
    float mm = v;
#pragma unroll
    for (int off = 32; off; off >>= 1) mm = fmaxf(mm, __shfl_xor(mm, off, 64));
    float ee = expf(v - mm);
    float ss = ee;
#pragma unroll
    for (int off = 32; off; off >>= 1) ss += __shfl_xor(ss, off, 64);
    w_s[lane] = ee / ss;
  }
  __syncthreads();

  float4 c1 = {0.f, 0.f, 0.f, 0.f}, c2 = {0.f, 0.f, 0.f, 0.f};
#pragma unroll
  for (int q = 0; q < 8; q++) {
    float wp = w_s[wid * 8 + q];
    c1.x += wp * f1[q].x; c1.y += wp * f1[q].y; c1.z += wp * f1[q].z; c1.w += wp * f1[q].w;
    c2.x += wp * f2[q].x; c2.y += wp * f2[q].y; c2.z += wp * f2[q].z; c2.w += wp * f2[q].w;
  }
  ((float4*)&cpart[wid][0])[lane] = c1;
  ((float4*)&cpart[wid][256])[lane] = c2;
  __syncthreads();

  float acc = 0.f;
#pragma unroll
  for (int w = 0; w < 8; w++) acc += cpart[w][tid];
  short hh = f2bf(acc);
  ctx_hi[(size_t)b * 512 + tid] = hh;
  ctx_lo[(size_t)b * 512 + tid] = f2bf(acc - bf2f(hh));
}

// ---- gates: [ctx|h][512x1024] @ Bcat (+Gemb[id]) -> LSTM. Tile 32x64, BK=64, 512 blocks. ----
// XCD-swizzled 1D grid: bid&7 -> 256-col span (per-XCD L2 holds its 1MB B slice + A stream).
__global__ __launch_bounds__(256) void gates_mfma_k(const short* __restrict__ ctx_hi, const short* __restrict__ ctx_lo,
                                                    const short* __restrict__ h_hi_in, const short* __restrict__ h_lo_in,
                                                    const int* __restrict__ targets, int t, int T,
                                                    const short* __restrict__ Ph, const short* __restrict__ Pl,
                                                    const float* __restrict__ Gemb_p,
                                                    float* __restrict__ cbuf,
                                                    short* __restrict__ h_hi_out, short* __restrict__ h_lo_out) {
  __shared__ short Ah[2][32][72], Al[2][32][72];
  __shared__ float Cs[32][68];
  int tid = threadIdx.x;
  int lane = tid & 63, wave = tid >> 6;
  int wn = wave * 16;
  int r15 = lane & 15, q8 = (lane >> 4) * 8;
  int bid = blockIdx.x;
  int xcd = bid & 7, sub = bid >> 3;           // sub < 64: 4 col-subblocks x 16 row-panels
  int col0 = xcd * 256 + (sub & 3) * 64;
  int row0 = (sub >> 2) * 32;
  int smA = tid >> 3, skA = (tid & 7) * 8;   // 32 rows x 64k, 8 shorts/thread
  const short* actx_h = ctx_hi + (size_t)(row0 + smA) * 512;
  const short* actx_l = ctx_lo + (size_t)(row0 + smA) * 512;
  const short* ahst_h = h_hi_in + (size_t)(row0 + smA) * 512;
  const short* ahst_l = h_lo_in + (size_t)(row0 + smA) * 512;
  int cg = (col0 >> 4) + wave;
  const short* pbh = Ph + (size_t)cg * 16384 + lane * 8;   // + (kt*2+ks)*512
  const short* pbl = Pl + (size_t)cg * 16384 + lane * 8;
  bf8 ah = *(const bf8*)(actx_h + skA), al = *(const bf8*)(actx_l + skA);
  bf8 bhc[2], blc[2], bhn[2], bln[2];
#pragma unroll
  for (int ks = 0; ks < 2; ks++) {
    bhc[ks] = *(const bf8*)(pbh + ks * 512);
    blc[ks] = *(const bf8*)(pbl + ks * 512);
  }
  f4 acc[2] = {};
#pragma unroll 2
  for (int kt = 0; kt < 16; kt++) {
    int buf = kt & 1;
    *(bf8*)&Ah[buf][smA][skA] = ah;
    *(bf8*)&Al[buf][smA][skA] = al;
    if (kt + 1 < 16) {
      int kk = (kt + 1) * 64 + skA;
      if (kk < 512) {
        ah = *(const bf8*)(actx_h + kk);
        al = *(const bf8*)(actx_l + kk);
      } else {
        ah = *(const bf8*)(ahst_h + kk - 512);
        al = *(const bf8*)(ahst_l + kk - 512);
      }
#pragma unroll
      for (int ks = 0; ks < 2; ks++) {
        bhn[ks] = *(const bf8*)(pbh + ((kt + 1) * 2 + ks) * 512);
        bln[ks] = *(const bf8*)(pbl + ((kt + 1) * 2 + ks) * 512);
      }
    }
    __syncthreads();
#pragma unroll
    for (int ks = 0; ks < 2; ks++) {
      bf8 fah[2], fal[2];
#pragma unroll
      for (int r = 0; r < 2; r++) {
        fah[r] = *(const bf8*)&Ah[buf][r * 16 + r15][ks * 32 + q8];
        fal[r] = *(const bf8*)&Al[buf][r * 16 + r15][ks * 32 + q8];
      }
#pragma unroll
      for (int r = 0; r < 2; r++) {
        acc[r] = __builtin_amdgcn_mfma_f32_16x16x32_bf16(fah[r], bhc[ks], acc[r], 0, 0, 0);
        acc[r] = __builtin_amdgcn_mfma_f32_16x16x32_bf16(fal[r], bhc[ks], acc[r], 0, 0, 0);
        acc[r] = __builtin_amdgcn_mfma_f32_16x16x32_bf16(fah[r], blc[ks], acc[r], 0, 0, 0);
      }
    }
#pragma unroll
    for (int ks = 0; ks < 2; ks++) { bhc[ks] = bhn[ks]; blc[ks] = bln[ks]; }
  }
  // stage C tile to LDS (MFMA C layout -> row/col), then LSTM epilogue
#pragma unroll
  for (int r = 0; r < 2; r++)
#pragma unroll
    for (int i = 0; i < 4; i++)
      Cs[r * 16 + (lane >> 4) * 4 + i][wn + r15] = acc[r][i];
  __syncthreads();
#pragma unroll
  for (int it = 0; it < 2; it++) {
    int idx = it * 256 + tid;
    int row = idx >> 4, jj = idx & 15;
    int b = row0 + row;
    int jg = (col0 >> 2) + jj;
    int id = (t == 0) ? 0 : targets[b * T + t - 1];
    float4 g4 = *(const float4*)(Gemb_p + (size_t)id * 2048 + col0 + jj * 4);
    float ig = sigmoidf_(Cs[row][jj * 4 + 0] + g4.x);
    float fg = sigmoidf_(Cs[row][jj * 4 + 1] + g4.y);
    float gg = tanhf(Cs[row][jj * 4 + 2] + g4.z);
    float og = sigmoidf_(Cs[row][jj * 4 + 3] + g4.w);
    float cn = fg * cbuf[(size_t)b * 512 + jg] + ig * gg;
    float hn = og * tanhf(cn);
    cbuf[(size_t)b * 512 + jg] = cn;
    short hh = f2bf(hn);
    h_hi_out[(size_t)b * 512 + jg] = hh;
    h_lo_out[(size_t)b * 512 + jg] = f2bf(hn - bf2f(hh));
  }
}

// ---- out GEMM: out = h_hist(bf16 hi/lo) @ Wo^T + bo. M=T*512, N=96, tile 64x96, split-bf16 MFMA ----
__global__ __launch_bounds__(256) void out_mfma_k(const short* __restrict__ Hh, const short* __restrict__ Hl,
                                                  const short* __restrict__ Ph, const short* __restrict__ Pl,
                                                  const float* __restrict__ bo, float* __restrict__ out, int T) {
  __shared__ short Ah[2][64][40], Al[2][64][40];
  int tid = threadIdx.x;
  int lane = tid & 63, wave = tid >> 6;
  int wm = (wave & 1) * 32, wn = (wave >> 1) * 48;
  int r15 = lane & 15, q8 = (lane >> 4) * 8;
  int row0 = blockIdx.x * 64;
  int smA = tid >> 2, skA = (tid & 3) * 8;
  const short* ahp = Hh + (size_t)(row0 + smA) * 512 + skA;
  const short* alp = Hl + (size_t)(row0 + smA) * 512 + skA;
  int cg0 = wn >> 4;
  const short* pbh = Ph + (size_t)cg0 * 8192 + lane * 8;
  const short* pbl = Pl + (size_t)cg0 * 8192 + lane * 8;
  bf8 ah = *(const bf8*)ahp, al = *(const bf8*)alp;
  bf8 bhc[3], blc[3], bhn[3], bln[3];
#pragma unroll
  for (int c = 0; c < 3; c++) {
    bhc[c] = *(const bf8*)(pbh + c * 8192);
    blc[c] = *(const bf8*)(pbl + c * 8192);
  }
  f4 acc[2][3] = {};
#pragma unroll 2
  for (int kt = 0; kt < 16; kt++) {
    int buf = kt & 1;
    *(bf8*)&Ah[buf][smA][skA] = ah;
    *(bf8*)&Al[buf][smA][skA] = al;
    if (kt + 1 < 16) {
      ahp += 32; alp += 32;
      ah = *(const bf8*)ahp; al = *(const bf8*)alp;
#pragma unroll
      for (int c = 0; c < 3; c++) {
        bhn[c] = *(const bf8*)(pbh + c * 8192 + (kt + 1) * 512);
        bln[c] = *(const bf8*)(pbl + c * 8192 + (kt + 1) * 512);
      }
    }
    __syncthreads();
    bf8 fah[2], fal[2];
#pragma unroll
    for (int r = 0; r < 2; r++) {
      fah[r] = *(const bf8*)&Ah[buf][wm + r * 16 + r15][q8];
      fal[r] = *(const bf8*)&Al[buf][wm + r * 16 + r15][q8];
    }
#pragma unroll
    for (int r = 0; r < 2; r++)
#pragma unroll
      for (int c = 0; c < 3; c++) {
        acc[r][c] = __builtin_amdgcn_mfma_f32_16x16x32_bf16(fah[r], bhc[c], acc[r][c], 0, 0, 0);
        acc[r][c] = __builtin_amdgcn_mfma_f32_16x16x32_bf16(fal[r], bhc[c], acc[r][c], 0, 0, 0);
        acc[r][c] = __builtin_amdgcn_mfma_f32_16x16x32_bf16(fah[r], blc[c], acc[r][c], 0, 0, 0);
      }
    __syncthreads();
#pragma unroll
    for (int c = 0; c < 3; c++) { bhc[c] = bhn[c]; blc[c] = bln[c]; }
  }
#pragma unroll
  for (int r = 0; r < 2; r++)
#pragma unroll
    for (int c = 0; c < 3; c++) {
      int col = wn + c * 16 + r15;
      float bv = bo[col];
#pragma unroll
      for (int i = 0; i < 4; i++) {
        int row = row0 + wm + r * 16 + (lane >> 4) * 4 + i;
        int tt = row >> 9, bb = row & 511;
        out[((size_t)bb * T + tt) * 96 + col] = acc[r][c][i] + bv;
      }
    }
}

extern "C" void kernel_launch(void* const* d_in, const int* in_sizes, int n_in,
                              void* d_out, int out_size, void* d_ws, size_t ws_size,
                              hipStream_t stream) {
  const float* features  = (const float*)d_in[0];
  const int*   targets   = (const int*)d_in[1];
  const float* Wfc       = (const float*)d_in[3];
  const float* bfc       = (const float*)d_in[4];
  const float* emb_table = (const float*)d_in[5];
  const float* Wa        = (const float*)d_in[6];
  const float* ba        = (const float*)d_in[7];
  const float* Wc        = (const float*)d_in[8];
  const float* bc        = (const float*)d_in[9];
  const float* Wih       = (const float*)d_in[10];
  const float* Whh       = (const float*)d_in[11];
  const float* bih       = (const float*)d_in[12];
  const float* bhh       = (const float*)d_in[13];
  const float* Wo        = (const float*)d_in[14];
  const float* bo        = (const float*)d_in[15];
  float* out = (float*)d_out;
  int T = in_sizes[1] / BATCH;  // 30

  char* base = (char*)d_ws;
  auto alloc = [&](size_t bytes) -> char* {
    char* p = base;
    base += (bytes + 255) & ~(size_t)255;
    return p;
  };
  float* feats   = (float*)alloc((size_t)BATCH * PPOS * HIDC * 4);
  short* f_hi    = (short*)alloc((size_t)BATCH * PPOS * HIDC * 2);
  short* f_lo    = (short*)alloc((size_t)BATCH * PPOS * HIDC * 2);
  float* WaT_emb = (float*)alloc(512 * 512 * 4);
  float* WcT     = (float*)alloc(1024 * 512 * 4);
  float* tmp     = (float*)alloc((size_t)512 * 2048 * 4);   // rows 0..511 (gemb)
  float* tmpT    = (float*)alloc((size_t)2048 * 512 * 4);   // rows 512..1023 transposed (build_btg)
  short* Wih_hi  = (short*)alloc((size_t)2048 * 512 * 2);
  short* Wih_lo  = (short*)alloc((size_t)2048 * 512 * 2);
  short* PBTg_hi = (short*)alloc((size_t)2048 * 1024 * 2);
  short* PBTg_lo = (short*)alloc((size_t)2048 * 1024 * 2);
  short* Pfc_hi  = (short*)alloc(512 * 512 * 2);
  short* Pfc_lo  = (short*)alloc(512 * 512 * 2);
  short* Pwa_hi  = (short*)alloc(512 * 512 * 2);
  short* Pwa_lo  = (short*)alloc(512 * 512 * 2);
  short* Pwo_hi  = (short*)alloc(96 * 512 * 2);
  short* Pwo_lo  = (short*)alloc(96 * 512 * 2);
  float* Gemb_p  = (float*)alloc(96 * 2048 * 4);
  float* Za      = (float*)alloc(96 * 512 * 4);
  float* bfused  = (float*)alloc(2048 * 4);
  float* cbuf    = (float*)alloc(BATCH * HIDC * 4);
  float* zbuf    = (float*)alloc((size_t)2 * BATCH * HIDC * 4);
  short* ctx_hi  = (short*)alloc(BATCH * HIDC * 2);
  short* ctx_lo  = (short*)alloc(BATCH * HIDC * 2);
  size_t slab = (size_t)BATCH * HIDC;                      // 262144 elems
  short* hist_hi = (short*)alloc((size_t)(T + 1) * slab * 2);
  short* hist_lo = (short*)alloc((size_t)(T + 1) * slab * 2);

  dim3 tb(32, 8);
  transpose_k<<<dim3(16, 16), tb, 0, stream>>>(Wa + 512, WaT_emb, 512, 512, 1024);
  transpose_k<<<dim3(32, 16), tb, 0, stream>>>(Wc, WcT, 512, 1024, 1024);

  // weight preprocessing
  split_k<<<(2048 * 512) / 256, 256, 0, stream>>>(Wih, Wih_hi, Wih_lo, 2048 * 512);
  pack_split_k<<<(512 * 512) / 256, 256, 0, stream>>>(Wfc, 512, Pfc_hi, Pfc_lo);
  pack_split_k<<<(512 * 512) / 256, 256, 0, stream>>>(Wa, 1024, Pwa_hi, Pwa_lo);
  pack_split_k<<<(96 * 512) / 256, 256, 0, stream>>>(Wo, 512, Pwo_hi, Pwo_lo);
  fsplit_k<<<(BATCH * PPOS * HIDC / 4) / 256, 256, 0, stream>>>(features, f_hi, f_lo);

  // tmp = WcT @ Wih^T; upper half row-major (gemb), lower half transposed (build_btg)
  tmp_mfma_k<<<dim3(16, 16), 256, 0, stream>>>(WcT, Wih_hi, Wih_lo, tmp, tmpT);

  bfuse_k<<<8, 256, 0, stream>>>(Wih, bc, bih, bhh, bfused);
  build_btg_pack_k<<<(2048 * 1024) / 256, 256, 0, stream>>>(tmpT, Whh, PBTg_hi, PBTg_lo);
  gemb_k<<<dim3(8, 24), 256, 0, stream>>>(emb_table, tmp, bfused, Gemb_p);
  za_k<<<dim3(2, 24), 256, 0, stream>>>(emb_table, WaT_emb, ba, Za);

  // feats = features @ Wfc.T + bfc, async-staged split-bf16 MFMA, tile 64x128
  feats_mfma_k<<<2048, 256, 0, stream>>>(f_hi, f_lo, Pfc_hi, Pfc_lo, bfc, feats);

  hipMemsetAsync(cbuf, 0, (size_t)BATCH * HIDC * 4, stream);
  hipMemsetAsync(hist_hi, 0, slab * 2, stream);
  hipMemsetAsync(hist_lo, 0, slab * 2, stream);

  for (int t = 0; t < T; t++) {
    const short* hin_hi = hist_hi + (size_t)t * slab;
    const short* hin_lo = hist_lo + (size_t)t * slab;
    short* hout_hi = hist_hi + (size_t)(t + 1) * slab;
    short* hout_lo = hist_lo + (size_t)(t + 1) * slab;
    z_mfma_k<<<dim3(16, 16, 2), 256, 0, stream>>>(hin_hi, hin_lo, Pwa_hi, Pwa_lo, zbuf);
    attn_fin_k<<<512, 512, 0, stream>>>(zbuf, targets, t, T, Za, feats, ctx_hi, ctx_lo);
    gates_mfma_k<<<512, 256, 0, stream>>>(ctx_hi, ctx_lo, hin_hi, hin_lo, targets, t, T,
                                          PBTg_hi, PBTg_lo, Gemb_p, cbuf, hout_hi, hout_lo);
  }
  // out = h_hist @ Wo^T + bo  (A = slabs 1..T of bf16 hi/lo history)
  out_mfma_k<<<(T * BATCH) / 64, 256, 0, stream>>>(hist_hi + slab, hist_lo + slab,
                                                   Pwo_hi, Pwo_lo, bo, out, T);
}

// Round 13
// 1241.814 us; speedup vs baseline: 1.0276x; 1.0068x over previous
//
#include <hip/hip_runtime.h>
#include <math.h>

// AttentionOCR: B=512, P=64, CIN=512, HID=512, EMB=512, NCLS=96, T=30
static constexpr int BATCH = 512;
static constexpr int PPOS  = 64;
static constexpr int HIDC  = 512;

typedef __attribute__((ext_vector_type(8))) short bf8;   // 8 bf16 = 4 VGPRs
typedef __attribute__((ext_vector_type(4))) short s4v;
typedef __attribute__((ext_vector_type(4))) float f4;

static __device__ __forceinline__ float sigmoidf_(float x) { return 1.f / (1.f + expf(-x)); }

static __device__ __forceinline__ short f2bf(float x) {
  unsigned u = __float_as_uint(x);
  u = u + 0x7FFF + ((u >> 16) & 1);   // round-nearest-even to bf16
  return (short)(u >> 16);
}
static __device__ __forceinline__ float bf2f(short s) {
  return __uint_as_float(((unsigned)(unsigned short)s) << 16);
}

// async global->LDS 16B per lane: LDS dest is wave-uniform base + lane*16 (linear).
static __device__ __forceinline__ void gld16(const short* g, short* l) {
  __builtin_amdgcn_global_load_lds((const __attribute__((address_space(1))) unsigned int*)g,
                                   (__attribute__((address_space(3))) unsigned int*)l, 16, 0, 0);
}

// ---------------- strided transpose: dst[C x R], dst[c][r] = src[r*ld + c] ----------------
__global__ void transpose_k(const float* __restrict__ src, float* __restrict__ dst, int R, int C, int ld) {
  __shared__ float tile[32][33];
  int c0 = blockIdx.x * 32, r0 = blockIdx.y * 32;
  int x = threadIdx.x;
  for (int yy = threadIdx.y; yy < 32; yy += 8) {
    int r = r0 + yy, c = c0 + x;
    if (r < R && c < C) tile[yy][x] = src[(size_t)r * ld + c];
  }
  __syncthreads();
  for (int yy = threadIdx.y; yy < 32; yy += 8) {
    int c = c0 + yy, r = r0 + x;
    if (r < R && c < C) dst[(size_t)c * R + r] = tile[x][yy];
  }
}

// ---------------- bfused[n] = bih[n] + bhh[n] + dot(Wih[n,:], bc) ----------------
__global__ void bfuse_k(const float* __restrict__ Wih, const float* __restrict__ bc,
                        const float* __restrict__ bih, const float* __restrict__ bhh,
                        float* __restrict__ bf) {
  int n = blockIdx.x * 256 + threadIdx.x;  // < 2048
  float s = bih[n] + bhh[n];
  const float* w = Wih + (size_t)n * 512;
  for (int m = 0; m < 512; m++) s += w[m] * bc[m];
  bf[n] = s;
}

// ---- split fp32 -> bf16 hi/lo (row-major) ----
__global__ void split_k(const float* __restrict__ src, short* __restrict__ hi, short* __restrict__ lo, int n) {
  int i = blockIdx.x * 256 + threadIdx.x;
  if (i < n) {
    float x = src[i];
    short h = f2bf(x);
    hi[i] = h;
    lo[i] = f2bf(x - bf2f(h));
  }
}

// ---- vectorized split of features: fp32 [32768x512] -> bf16 hi/lo ----
__global__ void fsplit_k(const float* __restrict__ src, short* __restrict__ hi, short* __restrict__ lo) {
  int i = blockIdx.x * 256 + threadIdx.x;  // over float4s
  float4 v = ((const float4*)src)[i];
  float a[4] = {v.x, v.y, v.z, v.w};
  s4v h4, l4;
#pragma unroll
  for (int j = 0; j < 4; j++) {
    short h = f2bf(a[j]);
    h4[j] = h;
    l4[j] = f2bf(a[j] - bf2f(h));
  }
  ((s4v*)hi)[i] = h4;
  ((s4v*)lo)[i] = l4;
}

// ---- fragment-pack + split: P[cg][kf][lane][8] = S[cg*16 + (lane&15)][kf*32 + (lane>>4)*8 + j] ----
__global__ void pack_split_k(const float* __restrict__ src, int ld,
                             short* __restrict__ hi, short* __restrict__ lo) {
  int idx = blockIdx.x * 256 + threadIdx.x;
  int j = idx & 7, lane = (idx >> 3) & 63, kf = (idx >> 9) & 15, cg = idx >> 13;
  int n = cg * 16 + (lane & 15);
  int k = kf * 32 + ((lane >> 4) << 3) + j;
  float v = src[(size_t)n * ld + k];
  short h = f2bf(v);
  hi[idx] = h;
  lo[idx] = f2bf(v - bf2f(h));
}

// ---- BTg packed from tmpT (row-major in k) + Whh: coalesced 32B-granule reads ----
__global__ void build_btg_pack_k(const float* __restrict__ tmpT, const float* __restrict__ Whh,
                                 short* __restrict__ hi, short* __restrict__ lo) {
  int idx = blockIdx.x * 256 + threadIdx.x;  // < 2097152
  int j = idx & 7, lane = (idx >> 3) & 63, kf = (idx >> 9) & 31, cg = idx >> 14;
  int cp = cg * 16 + (lane & 15);
  int k = kf * 32 + ((lane >> 4) << 3) + j;
  int jj = cp >> 2, g = cp & 3;
  int n = g * 512 + jj;
  float v = (k < 512) ? tmpT[(size_t)n * 512 + k] : Whh[(size_t)n * 512 + (k - 512)];
  short h = f2bf(v);
  hi[idx] = h;
  lo[idx] = f2bf(v - bf2f(h));
}

// ---- Gemb_p[96 x 2048] = (emb_table @ tmp[0:512]) + bfused, columns permuted. 4 e-rows/block ----
__global__ __launch_bounds__(256) void gemb_k(const float* __restrict__ emb_table, const float* __restrict__ tmp,
                                              const float* __restrict__ bfused, float* __restrict__ Gemb_p) {
  __shared__ float emb_s[4][512];
  int tid = threadIdx.x;
  int n0 = blockIdx.x * 256;
  int e0 = blockIdx.y * 4;
  for (int i = tid; i < 2048; i += 256)
    emb_s[i >> 9][i & 511] = emb_table[(size_t)(e0 + (i >> 9)) * 512 + (i & 511)];
  __syncthreads();
  int n = n0 + tid;
  float acc[4] = {};
  for (int k = 0; k < 512; k++) {
    float w = tmp[(size_t)k * 2048 + n];
#pragma unroll
    for (int e = 0; e < 4; e++) acc[e] += emb_s[e][k] * w;
  }
  int cp = (n & 511) * 4 + (n >> 9);
  float b = bfused[n];
#pragma unroll
  for (int e = 0; e < 4; e++) Gemb_p[(size_t)(e0 + e) * 2048 + cp] = acc[e] + b;
}

// ---- Za[96 x 512] = emb_table @ WaT_emb + ba. 4 e-rows/block ----
__global__ __launch_bounds__(256) void za_k(const float* __restrict__ emb_table, const float* __restrict__ WaT_emb,
                                            const float* __restrict__ ba, float* __restrict__ Za) {
  __shared__ float emb_s[4][512];
  int tid = threadIdx.x;
  int n0 = blockIdx.x * 256;
  int e0 = blockIdx.y * 4;
  for (int i = tid; i < 2048; i += 256)
    emb_s[i >> 9][i & 511] = emb_table[(size_t)(e0 + (i >> 9)) * 512 + (i & 511)];
  __syncthreads();
  int n = n0 + tid;
  float acc[4] = {};
  for (int k = 0; k < 512; k++) {
    float w = WaT_emb[(size_t)k * 512 + n];
#pragma unroll
    for (int e = 0; e < 4; e++) acc[e] += emb_s[e][k] * w;
  }
  float b = ba[n];
#pragma unroll
  for (int e = 0; e < 4; e++) Za[(size_t)(e0 + e) * 512 + n] = acc[e] + b;
}

// ---- feats: C[32768x512] = features @ Wfc^T (+bfc). Tile 64x128, grid 2048. (best config:
// 16 KB LDS, VGPR 64, ~35% occupancy.) A via async gload_lds; B packed direct from L2.
__global__ __launch_bounds__(256) void feats_mfma_k(const short* __restrict__ Fh, const short* __restrict__ Fl,
                                                    const short* __restrict__ Ph, const short* __restrict__ Pl,
                                                    const float* __restrict__ bias, float* __restrict__ C) {
  __shared__ short Ah[2][64][32], Al[2][64][32];
  int blk = blockIdx.x;
  int xt = (blk >> 3) & 3;
  int ytile = (blk >> 5) * 8 + (blk & 7);
  int row0 = ytile * 64, col0 = xt * 128;
  int tid = threadIdx.x;
  int lane = tid & 63, wave = tid >> 6;
  int wm = (wave & 1) * 32, wn = (wave >> 1) * 64;
  int r15 = lane & 15;
  int srow = 16 * wave + (lane >> 2);
  int sg = (lane & 3) ^ (srow & 3);
  const short* gAh = Fh + (size_t)(row0 + srow) * 512 + (sg << 3);
  const short* gAl = Fl + (size_t)(row0 + srow) * 512 + (sg << 3);
  int cg0 = (col0 + wn) >> 4;
  const short* pbh = Ph + (size_t)cg0 * 8192 + lane * 8;
  const short* pbl = Pl + (size_t)cg0 * 8192 + lane * 8;
  bf8 cbh[4], cbl[4], nbh[4], nbl[4];
#pragma unroll
  for (int c = 0; c < 4; c++) {
    cbh[c] = *(const bf8*)(pbh + c * 8192);
    cbl[c] = *(const bf8*)(pbl + c * 8192);
  }
  gld16(gAh, &Ah[0][16 * wave][0]);
  gld16(gAl, &Al[0][16 * wave][0]);
  __syncthreads();
  f4 acc[2][4] = {};
  for (int kt = 0; kt < 16; kt++) {
    int buf = kt & 1;
    if (kt + 1 < 16) {
      gld16(gAh + (kt + 1) * 32, &Ah[buf ^ 1][16 * wave][0]);
      gld16(gAl + (kt + 1) * 32, &Al[buf ^ 1][16 * wave][0]);
#pragma unroll
      for (int c = 0; c < 4; c++) {
        nbh[c] = *(const bf8*)(pbh + c * 8192 + (kt + 1) * 512);
        nbl[c] = *(const bf8*)(pbl + c * 8192 + (kt + 1) * 512);
      }
    }
    bf8 fah[2], fal[2];
#pragma unroll
    for (int r = 0; r < 2; r++) {
      int row = wm + r * 16 + r15;
      int off = row * 64 + ((((lane >> 4) ^ (r15 & 3)) << 4));
      fah[r] = *(const bf8*)((const char*)&Ah[buf][0][0] + off);
      fal[r] = *(const bf8*)((const char*)&Al[buf][0][0] + off);
    }
#pragma unroll
    for (int r = 0; r < 2; r++)
#pragma unroll
      for (int c = 0; c < 4; c++) {
        acc[r][c] = __builtin_amdgcn_mfma_f32_16x16x32_bf16(fah[r], cbh[c], acc[r][c], 0, 0, 0);
        acc[r][c] = __builtin_amdgcn_mfma_f32_16x16x32_bf16(fal[r], cbh[c], acc[r][c], 0, 0, 0);
        acc[r][c] = __builtin_amdgcn_mfma_f32_16x16x32_bf16(fah[r], cbl[c], acc[r][c], 0, 0, 0);
      }
    __syncthreads();   // drains gload_lds (kt+1 landed) + protects buf reuse
#pragma unroll
    for (int c = 0; c < 4; c++) { cbh[c] = nbh[c]; cbl[c] = nbl[c]; }
  }
#pragma unroll
  for (int r = 0; r < 2; r++)
#pragma unroll
    for (int c = 0; c < 4; c++) {
      int col = col0 + wn + c * 16 + r15;
      float bv = bias[col];
#pragma unroll
      for (int i = 0; i < 4; i++) {
        int row = row0 + wm + r * 16 + (lane >> 4) * 4 + i;
        C[(size_t)row * 512 + col] = acc[r][c][i] + bv;
      }
    }
}

// ---- tmp GEMM (setup): rows<512 -> tmp[512x2048] (gemb); rows>=512 -> tmpT[2048x512] (build_btg) ----
__global__ __launch_bounds__(256) void tmp_mfma_k(const float* __restrict__ A,
                                                  const short* __restrict__ BTh, const short* __restrict__ BTl,
                                                  float* __restrict__ C, float* __restrict__ CT) {
  __shared__ short Ah[2][64][40], Al[2][64][40], Bh[2][128][40], Bl[2][128][40];
  int row0 = blockIdx.y * 64, col0 = blockIdx.x * 128;
  int tid = threadIdx.x;
  int lane = tid & 63, wave = tid >> 6;
  int wm = (wave & 1) * 32, wn = (wave >> 1) * 64;
  int r15 = lane & 15, q8 = (lane >> 4) * 8;
  int smA = tid >> 2, skA = (tid & 3) * 8;
  int smB = tid >> 1, skB = (tid & 1) * 16;
  const float* Ap = A + (size_t)(row0 + smA) * 512 + skA;
  const short* Bhp = BTh + (size_t)(col0 + smB) * 512 + skB;
  const short* Blp = BTl + (size_t)(col0 + smB) * 512 + skB;
  float4 a0 = *(const float4*)Ap, a1 = *(const float4*)(Ap + 4);
  bf8 bh0 = *(const bf8*)Bhp, bh1 = *(const bf8*)(Bhp + 8);
  bf8 bl0 = *(const bf8*)Blp, bl1 = *(const bf8*)(Blp + 8);
  f4 acc[2][4] = {};
  for (int kt = 0; kt < 16; kt++) {
    int buf = kt & 1;
    {
      float av[8] = {a0.x, a0.y, a0.z, a0.w, a1.x, a1.y, a1.z, a1.w};
      bf8 ahv, alv;
#pragma unroll
      for (int i = 0; i < 8; i++) {
        short h = f2bf(av[i]);
        ahv[i] = h;
        alv[i] = f2bf(av[i] - bf2f(h));
      }
      *(bf8*)&Ah[buf][smA][skA] = ahv;
      *(bf8*)&Al[buf][smA][skA] = alv;
      *(bf8*)&Bh[buf][smB][skB] = bh0;
      *(bf8*)&Bh[buf][smB][skB + 8] = bh1;
      *(bf8*)&Bl[buf][smB][skB] = bl0;
      *(bf8*)&Bl[buf][smB][skB + 8] = bl1;
    }
    if (kt + 1 < 16) {
      Ap += 32; Bhp += 32; Blp += 32;
      a0 = *(const float4*)Ap; a1 = *(const float4*)(Ap + 4);
      bh0 = *(const bf8*)Bhp; bh1 = *(const bf8*)(Bhp + 8);
      bl0 = *(const bf8*)Blp; bl1 = *(const bf8*)(Blp + 8);
    }
    __syncthreads();
    bf8 fah[2], fal[2], fbh[4], fbl[4];
#pragma unroll
    for (int r = 0; r < 2; r++) {
      fah[r] = *(const bf8*)&Ah[buf][wm + r * 16 + r15][q8];
      fal[r] = *(const bf8*)&Al[buf][wm + r * 16 + r15][q8];
    }
#pragma unroll
    for (int c = 0; c < 4; c++) {
      fbh[c] = *(const bf8*)&Bh[buf][wn + c * 16 + r15][q8];
      fbl[c] = *(const bf8*)&Bl[buf][wn + c * 16 + r15][q8];
    }
#pragma unroll
    for (int r = 0; r < 2; r++)
#pragma unroll
      for (int c = 0; c < 4; c++) {
        acc[r][c] = __builtin_amdgcn_mfma_f32_16x16x32_bf16(fah[r], fbh[c], acc[r][c], 0, 0, 0);
        acc[r][c] = __builtin_amdgcn_mfma_f32_16x16x32_bf16(fal[r], fbh[c], acc[r][c], 0, 0, 0);
        acc[r][c] = __builtin_amdgcn_mfma_f32_16x16x32_bf16(fah[r], fbl[c], acc[r][c], 0, 0, 0);
      }
  }
#pragma unroll
  for (int r = 0; r < 2; r++)
#pragma unroll
    for (int c = 0; c < 4; c++) {
      int col = col0 + wn + c * 16 + r15;
#pragma unroll
      for (int i = 0; i < 4; i++) {
        int row = row0 + wm + r * 16 + (lane >> 4) * 4 + i;
        if (row < 512) C[(size_t)row * 2048 + col] = acc[r][c][i];
        else           CT[(size_t)col * 512 + (row - 512)] = acc[r][c][i];
      }
    }
}

// ---- per-step z GEMM: zbuf[2][512x512] = h_prev @ WaH^T (K-split halves), tile 32x32, BK=64 ----
// grid (16,16,2); A reg-staged -> LDS dbuf; B packed direct. (R9-best config.)
__global__ __launch_bounds__(256) void z_mfma_k(const short* __restrict__ h_hi, const short* __restrict__ h_lo,
                                                const short* __restrict__ Ph, const short* __restrict__ Pl,
                                                float* __restrict__ zbuf) {
  __shared__ short Ah[2][32][72], Al[2][32][72];
  int tid = threadIdx.x;
  int lane = tid & 63, wave = tid >> 6;
  int wm = (wave & 1) * 16, wn = (wave >> 1) * 16;
  int r15 = lane & 15, q4 = (lane >> 4) * 4, q8 = (lane >> 4) * 8;
  int row0 = blockIdx.y * 32, col0 = blockIdx.x * 32;
  int kz = blockIdx.z * 256;
  int sm = tid >> 3, sk = (tid & 7) * 8;
  const short* ahp = h_hi + (size_t)(row0 + sm) * 512 + kz + sk;
  const short* alp = h_lo + (size_t)(row0 + sm) * 512 + kz + sk;
  int cg = (col0 + wn) >> 4;
  const short* pbh = Ph + (size_t)cg * 8192 + (size_t)blockIdx.z * 4096 + lane * 8;
  const short* pbl = Pl + (size_t)cg * 8192 + (size_t)blockIdx.z * 4096 + lane * 8;
  bf8 ah = *(const bf8*)ahp, al = *(const bf8*)alp;
  bf8 bhc[2], blc[2], bhn[2], bln[2];
#pragma unroll
  for (int ks = 0; ks < 2; ks++) {
    bhc[ks] = *(const bf8*)(pbh + ks * 512);
    blc[ks] = *(const bf8*)(pbl + ks * 512);
  }
  f4 acc = {};
#pragma unroll 2
  for (int kt = 0; kt < 4; kt++) {
    int buf = kt & 1;
    *(bf8*)&Ah[buf][sm][sk] = ah;
    *(bf8*)&Al[buf][sm][sk] = al;
    if (kt + 1 < 4) {
      ahp += 64; alp += 64;
      ah = *(const bf8*)ahp; al = *(const bf8*)alp;
#pragma unroll
      for (int ks = 0; ks < 2; ks++) {
        bhn[ks] = *(const bf8*)(pbh + ((kt + 1) * 2 + ks) * 512);
        bln[ks] = *(const bf8*)(pbl + ((kt + 1) * 2 + ks) * 512);
      }
    }
    __syncthreads();
#pragma unroll
    for (int ks = 0; ks < 2; ks++) {
      bf8 fah = *(const bf8*)&Ah[buf][wm + r15][ks * 32 + q8];
      bf8 fal = *(const bf8*)&Al[buf][wm + r15][ks * 32 + q8];
      acc = __builtin_amdgcn_mfma_f32_16x16x32_bf16(fah, bhc[ks], acc, 0, 0, 0);
      acc = __builtin_amdgcn_mfma_f32_16x16x32_bf16(fal, bhc[ks], acc, 0, 0, 0);
      acc = __builtin_amdgcn_mfma_f32_16x16x32_bf16(fah, blc[ks], acc, 0, 0, 0);
    }
#pragma unroll
    for (int ks = 0; ks < 2; ks++) { bhc[ks] = bhn[ks]; blc[ks] = bln[ks]; }
  }
  float* zo = zbuf + (size_t)blockIdx.z * (512 * 512);
  int col = col0 + wn + r15;
#pragma unroll
  for (int i = 0; i < 4; i++)
    zo[(size_t)(row0 + wm + q4 + i) * 512 + col] = acc[i];
}

// ---- attn finish: softmax(z+Za[id]) -> scores -> softmax(P) -> ctx (bf16 hi/lo). ----
__global__ __launch_bounds__(512) void attn_fin_k(const float* __restrict__ zbuf,
                                                  const int* __restrict__ targets, int t, int T,
                                                  const float* __restrict__ Za, const float* __restrict__ feats,
                                                  short* __restrict__ ctx_hi, short* __restrict__ ctx_lo) {
  __shared__ float a_s[512];
  __shared__ float redm[8], reds[8];
  __shared__ float sc_s[64];
  __shared__ float w_s[64];
  __shared__ float cpart[8][512];
  int tid = threadIdx.x;
  int wid = tid >> 6, lane = tid & 63;
  int b = blockIdx.x;
  int id = (t == 0) ? 0 : targets[b * T + t - 1];

  const float4* fbase = (const float4*)(feats + (size_t)b * PPOS * 512);
  float4 f1[8], f2[8];
#pragma unroll
  for (int q = 0; q < 8; q++) {
    int p = wid * 8 + q;
    f1[q] = fbase[(size_t)p * 128 + lane];
    f2[q] = fbase[(size_t)p * 128 + 64 + lane];
  }

  float zv = zbuf[(size_t)b * 512 + tid] + zbuf[(size_t)(512 * 512) + b * 512 + tid]
           + Za[(size_t)id * 512 + tid];
  float m = zv;
#pragma unroll
  for (int off = 32; off; off >>= 1) m = fmaxf(m, __shfl_xor(m, off, 64));
  if (lane == 0) redm[wid] = m;
  __syncthreads();
  float M = redm[0];
#pragma unroll
  for (int w = 1; w < 8; w++) M = fmaxf(M, redm[w]);
  float e = expf(zv - M);
  float s = e;
#pragma unroll
  for (int off = 32; off; off >>= 1) s += __shfl_xor(s, off, 64);
  if (lane == 0) reds[wid] = s;
  __syncthreads();
  float S = 0.f;
#pragma unroll
  for (int w = 0; w < 8; w++) S += reds[w];
  a_s[tid] = e * (1.f / S);
  __syncthreads();

  float4 a1 = ((const float4*)a_s)[lane];
  float4 a2 = ((const float4*)a_s)[lane + 64];
#pragma unroll
  for (int q = 0; q < 8; q++) {
    float d = f1[q].x * a1.x + f1[q].y * a1.y + f1[q].z * a1.z + f1[q].w * a1.w
            + f2[q].x * a2.x + f2[q].y * a2.y + f2[q].z * a2.z + f2[q].w * a2.w;
#pragma unroll
    for (int off = 32; off; off >>= 1) d += __shfl_xor(d, off, 64);
    if (lane == 0) sc_s[wid * 8 + q] = d;
  }
  __syncthreads();

  if (wid == 0) {
    float v = sc_s[lane];
    float mm = v;
#pragma unroll
    for (int off = 32; off; off >>= 1) mm = fmaxf(mm, __shfl_xor(mm, off, 64));
    float ee = expf(v - mm);
    float ss = ee;
#pragma unroll
    for (int off = 32; off; off >>= 1) ss += __shfl_xor(ss, off, 64);
    w_s[lane] = ee / ss;
  }
  __syncthreads();

  float4 c1 = {0.f, 0.f, 0.f, 0.f}, c2 = {0.f, 0.f, 0.f, 0.f};
#pragma unroll
  for (int q = 0; q < 8; q++) {
    float wp = w_s[wid * 8 + q];
    c1.x += wp * f1[q].x; c1.y += wp * f1[q].y; c1.z += wp * f1[q].z; c1.w += wp * f1[q].w;
    c2.x += wp * f2[q].x; c2.y += wp * f2[q].y; c2.z += wp * f2[q].z; c2.w += wp * f2[q].w;
  }
  ((float4*)&cpart[wid][0])[lane] = c1;
  ((float4*)&cpart[wid][256])[lane] = c2;
  __syncthreads();

  float acc = 0.f;
#pragma unroll
  for (int w = 0; w < 8; w++) acc += cpart[w][tid];
  short hh = f2bf(acc);
  ctx_hi[(size_t)b * 512 + tid] = hh;
  ctx_lo[(size_t)b * 512 + tid] = f2bf(acc - bf2f(hh));
}

// ---- gates: [ctx|h][512x1024] @ Bcat (+Gemb[id]) -> LSTM. Tile 32x64, BK=64, 512 blocks. ----
// XCD-swizzled 1D grid: bid&7 -> 256-col span (per-XCD L2 holds its 1MB B slice + A stream).
__global__ __launch_bounds__(256) void gates_mfma_k(const short* __restrict__ ctx_hi, const short* __restrict__ ctx_lo,
                                                    const short* __restrict__ h_hi_in, const short* __restrict__ h_lo_in,
                                                    const int* __restrict__ targets, int t, int T,
                                                    const short* __restrict__ Ph, const short* __restrict__ Pl,
                                                    const float* __restrict__ Gemb_p,
                                                    float* __restrict__ cbuf,
                                                    short* __restrict__ h_hi_out, short* __restrict__ h_lo_out) {
  __shared__ short Ah[2][32][72], Al[2][32][72];
  __shared__ float Cs[32][68];
  int tid = threadIdx.x;
  int lane = tid & 63, wave = tid >> 6;
  int wn = wave * 16;
  int r15 = lane & 15, q8 = (lane >> 4) * 8;
  int bid = blockIdx.x;
  int xcd = bid & 7, sub = bid >> 3;           // sub < 64: 4 col-subblocks x 16 row-panels
  int col0 = xcd * 256 + (sub & 3) * 64;
  int row0 = (sub >> 2) * 32;
  int smA = tid >> 3, skA = (tid & 7) * 8;   // 32 rows x 64k, 8 shorts/thread
  const short* actx_h = ctx_hi + (size_t)(row0 + smA) * 512;
  const short* actx_l = ctx_lo + (size_t)(row0 + smA) * 512;
  const short* ahst_h = h_hi_in + (size_t)(row0 + smA) * 512;
  const short* ahst_l = h_lo_in + (size_t)(row0 + smA) * 512;
  int cg = (col0 >> 4) + wave;
  const short* pbh = Ph + (size_t)cg * 16384 + lane * 8;   // + (kt*2+ks)*512
  const short* pbl = Pl + (size_t)cg * 16384 + lane * 8;
  bf8 ah = *(const bf8*)(actx_h + skA), al = *(const bf8*)(actx_l + skA);
  bf8 bhc[2], blc[2], bhn[2], bln[2];
#pragma unroll
  for (int ks = 0; ks < 2; ks++) {
    bhc[ks] = *(const bf8*)(pbh + ks * 512);
    blc[ks] = *(const bf8*)(pbl + ks * 512);
  }
  f4 acc[2] = {};
#pragma unroll 2
  for (int kt = 0; kt < 16; kt++) {
    int buf = kt & 1;
    *(bf8*)&Ah[buf][smA][skA] = ah;
    *(bf8*)&Al[buf][smA][skA] = al;
    if (kt + 1 < 16) {
      int kk = (kt + 1) * 64 + skA;
      if (kk < 512) {
        ah = *(const bf8*)(actx_h + kk);
        al = *(const bf8*)(actx_l + kk);
      } else {
        ah = *(const bf8*)(ahst_h + kk - 512);
        al = *(const bf8*)(ahst_l + kk - 512);
      }
#pragma unroll
      for (int ks = 0; ks < 2; ks++) {
        bhn[ks] = *(const bf8*)(pbh + ((kt + 1) * 2 + ks) * 512);
        bln[ks] = *(const bf8*)(pbl + ((kt + 1) * 2 + ks) * 512);
      }
    }
    __syncthreads();
#pragma unroll
    for (int ks = 0; ks < 2; ks++) {
      bf8 fah[2], fal[2];
#pragma unroll
      for (int r = 0; r < 2; r++) {
        fah[r] = *(const bf8*)&Ah[buf][r * 16 + r15][ks * 32 + q8];
        fal[r] = *(const bf8*)&Al[buf][r * 16 + r15][ks * 32 + q8];
      }
#pragma unroll
      for (int r = 0; r < 2; r++) {
        acc[r] = __builtin_amdgcn_mfma_f32_16x16x32_bf16(fah[r], bhc[ks], acc[r], 0, 0, 0);
        acc[r] = __builtin_amdgcn_mfma_f32_16x16x32_bf16(fal[r], bhc[ks], acc[r], 0, 0, 0);
        acc[r] = __builtin_amdgcn_mfma_f32_16x16x32_bf16(fah[r], blc[ks], acc[r], 0, 0, 0);
      }
    }
#pragma unroll
    for (int ks = 0; ks < 2; ks++) { bhc[ks] = bhn[ks]; blc[ks] = bln[ks]; }
  }
  // stage C tile to LDS (MFMA C layout -> row/col), then LSTM epilogue
#pragma unroll
  for (int r = 0; r < 2; r++)
#pragma unroll
    for (int i = 0; i < 4; i++)
      Cs[r * 16 + (lane >> 4) * 4 + i][wn + r15] = acc[r][i];
  __syncthreads();
#pragma unroll
  for (int it = 0; it < 2; it++) {
    int idx = it * 256 + tid;
    int row = idx >> 4, jj = idx & 15;
    int b = row0 + row;
    int jg = (col0 >> 2) + jj;
    int id = (t == 0) ? 0 : targets[b * T + t - 1];
    float4 g4 = *(const float4*)(Gemb_p + (size_t)id * 2048 + col0 + jj * 4);
    float ig = sigmoidf_(Cs[row][jj * 4 + 0] + g4.x);
    float fg = sigmoidf_(Cs[row][jj * 4 + 1] + g4.y);
    float gg = tanhf(Cs[row][jj * 4 + 2] + g4.z);
    float og = sigmoidf_(Cs[row][jj * 4 + 3] + g4.w);
    float cn = fg * cbuf[(size_t)b * 512 + jg] + ig * gg;
    float hn = og * tanhf(cn);
    cbuf[(size_t)b * 512 + jg] = cn;
    short hh = f2bf(hn);
    h_hi_out[(size_t)b * 512 + jg] = hh;
    h_lo_out[(size_t)b * 512 + jg] = f2bf(hn - bf2f(hh));
  }
}

// ---- out GEMM: out = h_hist(bf16 hi/lo) @ Wo^T + bo. M=T*512, N=96, tile 64x96, split-bf16 MFMA ----
__global__ __launch_bounds__(256) void out_mfma_k(const short* __restrict__ Hh, const short* __restrict__ Hl,
                                                  const short* __restrict__ Ph, const short* __restrict__ Pl,
                                                  const float* __restrict__ bo, float* __restrict__ out, int T) {
  __shared__ short Ah[2][64][40], Al[2][64][40];
  int tid = threadIdx.x;
  int lane = tid & 63, wave = tid >> 6;
  int wm = (wave & 1) * 32, wn = (wave >> 1) * 48;
  int r15 = lane & 15, q8 = (lane >> 4) * 8;
  int row0 = blockIdx.x * 64;
  int smA = tid >> 2, skA = (tid & 3) * 8;
  const short* ahp = Hh + (size_t)(row0 + smA) * 512 + skA;
  const short* alp = Hl + (size_t)(row0 + smA) * 512 + skA;
  int cg0 = wn >> 4;
  const short* pbh = Ph + (size_t)cg0 * 8192 + lane * 8;
  const short* pbl = Pl + (size_t)cg0 * 8192 + lane * 8;
  bf8 ah = *(const bf8*)ahp, al = *(const bf8*)alp;
  bf8 bhc[3], blc[3], bhn[3], bln[3];
#pragma unroll
  for (int c = 0; c < 3; c++) {
    bhc[c] = *(const bf8*)(pbh + c * 8192);
    blc[c] = *(const bf8*)(pbl + c * 8192);
  }
  f4 acc[2][3] = {};
#pragma unroll 2
  for (int kt = 0; kt < 16; kt++) {
    int buf = kt & 1;
    *(bf8*)&Ah[buf][smA][skA] = ah;
    *(bf8*)&Al[buf][smA][skA] = al;
    if (kt + 1 < 16) {
      ahp += 32; alp += 32;
      ah = *(const bf8*)ahp; al = *(const bf8*)alp;
#pragma unroll
      for (int c = 0; c < 3; c++) {
        bhn[c] = *(const bf8*)(pbh + c * 8192 + (kt + 1) * 512);
        bln[c] = *(const bf8*)(pbl + c * 8192 + (kt + 1) * 512);
      }
    }
    __syncthreads();
    bf8 fah[2], fal[2];
#pragma unroll
    for (int r = 0; r < 2; r++) {
      fah[r] = *(const bf8*)&Ah[buf][wm + r * 16 + r15][q8];
      fal[r] = *(const bf8*)&Al[buf][wm + r * 16 + r15][q8];
    }
#pragma unroll
    for (int r = 0; r < 2; r++)
#pragma unroll
      for (int c = 0; c < 3; c++) {
        acc[r][c] = __builtin_amdgcn_mfma_f32_16x16x32_bf16(fah[r], bhc[c], acc[r][c], 0, 0, 0);
        acc[r][c] = __builtin_amdgcn_mfma_f32_16x16x32_bf16(fal[r], bhc[c], acc[r][c], 0, 0, 0);
        acc[r][c] = __builtin_amdgcn_mfma_f32_16x16x32_bf16(fah[r], blc[c], acc[r][c], 0, 0, 0);
      }
    __syncthreads();
#pragma unroll
    for (int c = 0; c < 3; c++) { bhc[c] = bhn[c]; blc[c] = bln[c]; }
  }
#pragma unroll
  for (int r = 0; r < 2; r++)
#pragma unroll
    for (int c = 0; c < 3; c++) {
      int col = wn + c * 16 + r15;
      float bv = bo[col];
#pragma unroll
      for (int i = 0; i < 4; i++) {
        int row = row0 + wm + r * 16 + (lane >> 4) * 4 + i;
        int tt = row >> 9, bb = row & 511;
        out[((size_t)bb * T + tt) * 96 + col] = acc[r][c][i] + bv;
      }
    }
}

extern "C" void kernel_launch(void* const* d_in, const int* in_sizes, int n_in,
                              void* d_out, int out_size, void* d_ws, size_t ws_size,
                              hipStream_t stream) {
  const float* features  = (const float*)d_in[0];
  const int*   targets   = (const int*)d_in[1];
  const float* Wfc       = (const float*)d_in[3];
  const float* bfc       = (const float*)d_in[4];
  const float* emb_table = (const float*)d_in[5];
  const float* Wa        = (const float*)d_in[6];
  const float* ba        = (const float*)d_in[7];
  const float* Wc        = (const float*)d_in[8];
  const float* bc        = (const float*)d_in[9];
  const float* Wih       = (const float*)d_in[10];
  const float* Whh       = (const float*)d_in[11];
  const float* bih       = (const float*)d_in[12];
  const float* bhh       = (const float*)d_in[13];
  const float* Wo        = (const float*)d_in[14];
  const float* bo        = (const float*)d_in[15];
  float* out = (float*)d_out;
  int T = in_sizes[1] / BATCH;  // 30

  char* base = (char*)d_ws;
  auto alloc = [&](size_t bytes) -> char* {
    char* p = base;
    base += (bytes + 255) & ~(size_t)255;
    return p;
  };
  float* feats   = (float*)alloc((size_t)BATCH * PPOS * HIDC * 4);
  short* f_hi    = (short*)alloc((size_t)BATCH * PPOS * HIDC * 2);
  short* f_lo    = (short*)alloc((size_t)BATCH * PPOS * HIDC * 2);
  float* WaT_emb = (float*)alloc(512 * 512 * 4);
  float* WcT     = (float*)alloc(1024 * 512 * 4);
  float* tmp     = (float*)alloc((size_t)512 * 2048 * 4);   // rows 0..511 (gemb)
  float* tmpT    = (float*)alloc((size_t)2048 * 512 * 4);   // rows 512..1023 transposed (build_btg)
  short* Wih_hi  = (short*)alloc((size_t)2048 * 512 * 2);
  short* Wih_lo  = (short*)alloc((size_t)2048 * 512 * 2);
  short* PBTg_hi = (short*)alloc((size_t)2048 * 1024 * 2);
  short* PBTg_lo = (short*)alloc((size_t)2048 * 1024 * 2);
  short* Pfc_hi  = (short*)alloc(512 * 512 * 2);
  short* Pfc_lo  = (short*)alloc(512 * 512 * 2);
  short* Pwa_hi  = (short*)alloc(512 * 512 * 2);
  short* Pwa_lo  = (short*)alloc(512 * 512 * 2);
  short* Pwo_hi  = (short*)alloc(96 * 512 * 2);
  short* Pwo_lo  = (short*)alloc(96 * 512 * 2);
  float* Gemb_p  = (float*)alloc(96 * 2048 * 4);
  float* Za      = (float*)alloc(96 * 512 * 4);
  float* bfused  = (float*)alloc(2048 * 4);
  float* cbuf    = (float*)alloc(BATCH * HIDC * 4);
  float* zbuf    = (float*)alloc((size_t)2 * BATCH * HIDC * 4);
  short* ctx_hi  = (short*)alloc(BATCH * HIDC * 2);
  short* ctx_lo  = (short*)alloc(BATCH * HIDC * 2);
  size_t slab = (size_t)BATCH * HIDC;                      // 262144 elems
  short* hist_hi = (short*)alloc((size_t)(T + 1) * slab * 2);
  short* hist_lo = (short*)alloc((size_t)(T + 1) * slab * 2);

  dim3 tb(32, 8);
  transpose_k<<<dim3(16, 16), tb, 0, stream>>>(Wa + 512, WaT_emb, 512, 512, 1024);
  transpose_k<<<dim3(32, 16), tb, 0, stream>>>(Wc, WcT, 512, 1024, 1024);

  // weight preprocessing
  split_k<<<(2048 * 512) / 256, 256, 0, stream>>>(Wih, Wih_hi, Wih_lo, 2048 * 512);
  pack_split_k<<<(512 * 512) / 256, 256, 0, stream>>>(Wfc, 512, Pfc_hi, Pfc_lo);
  pack_split_k<<<(512 * 512) / 256, 256, 0, stream>>>(Wa, 1024, Pwa_hi, Pwa_lo);
  pack_split_k<<<(96 * 512) / 256, 256, 0, stream>>>(Wo, 512, Pwo_hi, Pwo_lo);
  fsplit_k<<<(BATCH * PPOS * HIDC / 4) / 256, 256, 0, stream>>>(features, f_hi, f_lo);

  // tmp = WcT @ Wih^T; upper half row-major (gemb), lower half transposed (build_btg)
  tmp_mfma_k<<<dim3(16, 16), 256, 0, stream>>>(WcT, Wih_hi, Wih_lo, tmp, tmpT);

  bfuse_k<<<8, 256, 0, stream>>>(Wih, bc, bih, bhh, bfused);
  build_btg_pack_k<<<(2048 * 1024) / 256, 256, 0, stream>>>(tmpT, Whh, PBTg_hi, PBTg_lo);
  gemb_k<<<dim3(8, 24), 256, 0, stream>>>(emb_table, tmp, bfused, Gemb_p);
  za_k<<<dim3(2, 24), 256, 0, stream>>>(emb_table, WaT_emb, ba, Za);

  // feats = features @ Wfc.T + bfc, async-staged split-bf16 MFMA, tile 64x128
  feats_mfma_k<<<2048, 256, 0, stream>>>(f_hi, f_lo, Pfc_hi, Pfc_lo, bfc, feats);

  hipMemsetAsync(cbuf, 0, (size_t)BATCH * HIDC * 4, stream);
  hipMemsetAsync(hist_hi, 0, slab * 2, stream);
  hipMemsetAsync(hist_lo, 0, slab * 2, stream);

  for (int t = 0; t < T; t++) {
    const short* hin_hi = hist_hi + (size_t)t * slab;
    const short* hin_lo = hist_lo + (size_t)t * slab;
    short* hout_hi = hist_hi + (size_t)(t + 1) * slab;
    short* hout_lo = hist_lo + (size_t)(t + 1) * slab;
    z_mfma_k<<<dim3(16, 16, 2), 256, 0, stream>>>(hin_hi, hin_lo, Pwa_hi, Pwa_lo, zbuf);
    attn_fin_k<<<512, 512, 0, stream>>>(zbuf, targets, t, T, Za, feats, ctx_hi, ctx_lo);
    gates_mfma_k<<<512, 256, 0, stream>>>(ctx_hi, ctx_lo, hin_hi, hin_lo, targets, t, T,
                                          PBTg_hi, PBTg_lo, Gemb_p, cbuf, hout_hi, hout_lo);
  }
  // out = h_hist @ Wo^T + bo  (A = slabs 1..T of bf16 hi/lo history)
  out_mfma_k<<<(T * BATCH) / 64, 256, 0, stream>>>(hist_hi + slab, hist_lo + slab,
                                                   Pwo_hi, Pwo_lo, bo, out, T);
}